// Round 12
// baseline (346.552 us; speedup 1.0000x reference)
//
#include <hip/hip_runtime.h>

// FluxUNet fused block — round 12: force qkv to <=128 VGPR via __launch_bounds__(256,4)
// (132 VGPR crossed the 128 occupancy cliff -> 2 blocks/CU; this restores 4).
// Everything else identical to round 11.
// B=8, C=512, HW=1024, S=77, E=768, NH=8, HD=64, HID=2048, T=1101.
constexpr int BATCH = 8, CH = 512, HWN = 1024, SEQ = 77, EMB = 768;
constexpr int NHEAD = 8, HDIM = 64, HIDDEN = 2048, TTOT = 1101;
constexpr int VSTRIDE = 1152;  // padded t-stride for transposed V

typedef short bhalf8 __attribute__((ext_vector_type(8)));
typedef float f32x4 __attribute__((ext_vector_type(4)));

__device__ __forceinline__ unsigned short f2bf(float f) {
    unsigned u = __builtin_bit_cast(unsigned, f);
    unsigned r = (u + 0x7fffu + ((u >> 16) & 1u)) >> 16;
    return (unsigned short)r;
}
__device__ __forceinline__ unsigned cvtpk(float a, float b) {
    unsigned r;
    asm("v_cvt_pk_bf16_f32 %0, %1, %2" : "=v"(r) : "v"(a), "v"(b));
    return r;
}
// gelu_tanh via identity 0.5(1+tanh(u)) = 1 - 1/(e^{2u}+1); e^{2u} = 2^{2u*log2e}.
__device__ __forceinline__ float gelu_fast(float v) {
    float c = v * v * v;
    float z = fmaf(v, 2.3022082f, c * 0.10294324f);
    float e = exp2f(z) + 1.0f;
    float r;
    asm("v_rcp_f32 %0, %1" : "=v"(r) : "v"(e));
    return v - v * r;
}
// XOR-swizzle on a 128B-row-stride LDS tile (region base must be 1024B-aligned).
__device__ __forceinline__ int swz(int b) { return b ^ ((b >> 3) & 0x70); }

// async global->LDS 16B: LDS dest = wave-uniform base + lane*16.
__device__ __forceinline__ void gload16(const void* g, void* l) {
    __builtin_amdgcn_global_load_lds(
        (const __attribute__((address_space(1))) unsigned int*)g,
        (__attribute__((address_space(3))) unsigned int*)l, 16, 0, 0);
}

// ---------- merged prep: casts (y<6), rope table (y==6),
// ----------             y==7: mod bias-init / silu(emb) ----------
struct PrepArgs {
    const float* src[6];
    unsigned short* dst[6];
    int n[6];
    const float* freqs;
    float* ct;
    const float* emb;
    const float* mbias;
    float* mod;
    float* se;       // silu(emb) [8][768]
};
__global__ void k_prep(PrepArgs a) {
    int y = blockIdx.y;
    int bx = blockIdx.x;
    int tid = threadIdx.x;
    if (y < 6) {
        int i = (bx * 256 + tid) * 4;
        if (i >= a.n[y]) return;
        float4 v = *(const float4*)&a.src[y][i];
        ushort4 o = {f2bf(v.x), f2bf(v.y), f2bf(v.z), f2bf(v.w)};
        *(ushort4*)&a.dst[y][i] = o;
    } else if (y == 6) {
        int i = bx * 256 + tid;
        if (i >= TTOT * 32) return;
        int t = i >> 5, j = i & 31;
        float ang;
        if (t < HWN) {
            ang = (float)(t >> 5) * a.freqs[2 * j] + (float)(t & 31) * a.freqs[2 * j + 1];
        } else {
            float inv = expf(-(float)j * (9.210340371976184f / 32.0f));
            ang = (float)(t - HWN) * inv;
        }
        a.ct[i * 2] = cosf(ang);
        a.ct[i * 2 + 1] = sinf(ang);
    } else {
        if (bx < 24) {            // mod = bias (atomic partials land on top)
            int i = bx * 1024 + tid * 4;           // i = b*3072 + j, j%4==0
            int j = i - (i / (6 * CH)) * (6 * CH);
            *(float4*)&a.mod[i] = *(const float4*)&a.mbias[j];
        } else if (bx >= 32 && bx < 38) {  // silu(final_emb) -> se [6144 floats]
            int i = (bx - 32) * 1024 + tid * 4;
            float4 v = *(const float4*)&a.emb[i];
            float4 o;
            o.x = v.x / (1.0f + expf(-v.x));
            o.y = v.y / (1.0f + expf(-v.y));
            o.z = v.z / (1.0f + expf(-v.z));
            o.w = v.w / (1.0f + expf(-v.w));
            *(float4*)&a.se[i] = o;
        }
    }
}

// ---------- modulation partials: mod[b][j] += sum_{e in chunk} se[b][e] * w[e][j] ----------
__global__ __launch_bounds__(256) void k_mod(const float* __restrict__ se,
        const float* __restrict__ w, float* __restrict__ mod) {
    int jb = blockIdx.x, b = blockIdx.y, ec = blockIdx.z;
    int j = jb * 256 + threadIdx.x;
    const float* sb = se + b * EMB + ec * 96;
    const float* wb = w + (size_t)(ec * 96) * (6 * CH) + j;
    float acc = 0.f;
    #pragma unroll 8
    for (int e = 0; e < 96; ++e) acc = fmaf(sb[e], wb[(size_t)e * (6 * CH)], acc);
    atomicAdd(&mod[b * (6 * CH) + j], acc);
}

// ------- RMSNorm(channel) + adaLN modulate + transpose -> bf16 token-major -------
__global__ __launch_bounds__(256) void k_rms2d_mod_t(const float* __restrict__ xin,
        const float* __restrict__ sw, const float* __restrict__ mod, int shoff, int scoff,
        unsigned short* __restrict__ outp) {
    __shared__ float part[4][64];
    __shared__ float rinv[64];
    int b = blockIdx.y;
    int n0 = blockIdx.x * 64;
    int tid = threadIdx.x;
    const float* xb = xin + (size_t)b * CH * HWN;
    {
        int n = n0 + (tid & 63);
        int cg = tid >> 6;
        float ss = 0.f;
        #pragma unroll 8
        for (int c = cg * 128; c < cg * 128 + 128; ++c) {
            float v = xb[(size_t)c * HWN + n];
            ss = fmaf(v, v, ss);
        }
        part[cg][tid & 63] = ss;
    }
    __syncthreads();
    if (tid < 64) {
        float s = part[0][tid] + part[1][tid] + part[2][tid] + part[3][tid];
        rinv[tid] = rsqrtf(s * (1.0f / CH) + 1e-6f);
    }
    __syncthreads();
    int n = n0 + (tid >> 2);
    int cq = tid & 3;
    float r = rinv[tid >> 2];
    const float* mb = mod + b * (6 * CH);
    unsigned short* orow = outp + ((size_t)(b * HWN + n)) * CH;
    for (int jc = 0; jc < 16; ++jc) {
        int c = cq * 128 + jc * 8;
        bhalf8 o;
        #pragma unroll
        for (int u = 0; u < 8; ++u) {
            int cc = c + u;
            float v = xb[(size_t)cc * HWN + n];
            float y = v * r * sw[cc] * (1.0f + mb[scoff + cc]) + mb[shoff + cc];
            o[u] = (short)f2bf(y);
        }
        *(bhalf8*)&orow[c] = o;
    }
}

// ------- bf16 MFMA GEMM, 2-phase double-buffered (prefetch t+1 before compute t) -------
// A [M][K], Bt [N][K] bf16 row-major. K%64==0, N%BN==0, M row-clamped.
// EPI=1: f32 channel-major residual+gate (BM=128).  EPI=2: bf16 gelu token-major.
template <int EPI, int BM, int BN>
__global__ __launch_bounds__(256) void k_gemm_mfma(
        const unsigned short* __restrict__ A, const unsigned short* __restrict__ Bt,
        void* __restrict__ OutV, int M, int N, int K,
        const float* __restrict__ bias, const float* __restrict__ gate,
        const float* __restrict__ res) {
    constexpr int WM = BM / 2, WN = BN / 2;
    constexpr int MI = WM / 16, NI = WN / 16;
    constexpr int CA = BM / 8, CB = BN / 8, CW = (CA + CB) / 4;
    constexpr int BUF = (BM + BN) * 128;
    __shared__ __align__(1024) char SM[2 * BUF];
    int tid = threadIdx.x;
    int w = tid >> 6, l = tid & 63, lg = l >> 4, ll = l & 15;
    int wr = w >> 1, wc = w & 1;
    int m0 = blockIdx.y * BM, n0 = blockIdx.x * BN;
    int r8 = l >> 3, c16 = (l & 7) * 16;
    f32x4 acc[MI][NI] = {};
    const char* Ac = (const char*)A;
    const char* Bc = (const char*)Bt;
    size_t rowBytes = (size_t)K * 2;
    int nt = K >> 6;

    auto stage = [&](int t, int bsel) {
        char* As = SM + bsel * BUF;
        char* Bs = As + BM * 128;
        int k0 = t * 64;
        #pragma unroll
        for (int i = 0; i < CW; ++i) {
            int c = w * CW + i;
            if (c < CA) {
                int row = c * 8 + r8;
                int off = c16 ^ ((row & 7) << 4);
                int ar = m0 + row;
                if (ar > M - 1) ar = M - 1;
                gload16(Ac + (size_t)ar * rowBytes + k0 * 2 + off, As + c * 1024);
            } else {
                int cc = c - CA;
                int row = cc * 8 + r8;
                int off = c16 ^ ((row & 7) << 4);
                gload16(Bc + (size_t)(n0 + row) * rowBytes + k0 * 2 + off, Bs + cc * 1024);
            }
        }
    };
    stage(0, 0);
    __syncthreads();  // tile 0 landed
    int cur = 0;
    for (int t = 0; t < nt; ++t) {
        if (t + 1 < nt) stage(t + 1, cur ^ 1);  // latency hides under compute of tile t
        char* As = SM + cur * BUF;
        char* Bs = As + BM * 128;
        #pragma unroll
        for (int ks = 0; ks < 2; ++ks) {
            bhalf8 af[MI], bf[NI];
            #pragma unroll
            for (int mi = 0; mi < MI; ++mi)
                af[mi] = *(const bhalf8*)(As + swz((wr * WM + mi * 16 + ll) * 128 + ks * 64 + lg * 16));
            #pragma unroll
            for (int ni = 0; ni < NI; ++ni)
                bf[ni] = *(const bhalf8*)(Bs + swz((wc * WN + ni * 16 + ll) * 128 + ks * 64 + lg * 16));
            __builtin_amdgcn_s_setprio(1);
            #pragma unroll
            for (int mi = 0; mi < MI; ++mi)
                #pragma unroll
                for (int ni = 0; ni < NI; ++ni)
                    acc[mi][ni] = __builtin_amdgcn_mfma_f32_16x16x32_bf16(af[mi], bf[ni], acc[mi][ni], 0, 0, 0);
            __builtin_amdgcn_s_setprio(0);
        }
        __syncthreads();  // next tile landed; all waves done with cur buffers
        cur ^= 1;
    }
    if (EPI == 2) {
        unsigned short* Out = (unsigned short*)OutV;
        #pragma unroll
        for (int mi = 0; mi < MI; ++mi)
            #pragma unroll
            for (int ni = 0; ni < NI; ++ni) {
                int col = n0 + wc * WN + ni * 16 + ll;
                float bv = bias[col];
                #pragma unroll
                for (int r = 0; r < 4; ++r) {
                    int mrow = m0 + wr * WM + mi * 16 + 4 * lg + r;
                    Out[(size_t)mrow * N + col] = f2bf(gelu_fast(acc[mi][ni][r] + bv));
                }
            }
    } else {
        float* Out = (float*)OutV;
        int bidx = m0 >> 10;
        int hw0 = m0 & 1023;
        const float* resb = res + (size_t)bidx * N * HWN;
        float* outb_ = Out + (size_t)bidx * N * HWN;
        #pragma unroll
        for (int ni = 0; ni < NI; ++ni) {
            int ch = n0 + wc * WN + ni * 16 + ll;
            float g = gate[bidx * (6 * CH) + ch];
            float bv = bias[ch];
            #pragma unroll
            for (int mi = 0; mi < MI; ++mi) {
                int t = hw0 + wr * WM + mi * 16 + 4 * lg;
                float4 r4 = *(const float4*)&resb[(size_t)ch * HWN + t];
                f32x4 a = acc[mi][ni];
                float4 o;
                o.x = r4.x + g * (a[0] + bv);
                o.y = r4.y + g * (a[1] + bv);
                o.z = r4.z + g * (a[2] + bv);
                o.w = r4.w + g * (a[3] + bv);
                *(float4*)&outb_[(size_t)ch * HWN + t] = o;
            }
        }
    }
}

// ------- qkv GEMM with fused RoPE + qk-RMSNorm + head-split + V-transpose -------
// COND=0: A=hmod [8192][512], grid (12,64), nOff=0.
// COND=1: A=condb [616][768], grid (8,5), nOff=512.  All shapes compile-time.
// __launch_bounds__(256,4): forces <=128 VGPR (4 waves/EU -> 16 waves/CU) — r11's
// 132 VGPR crossed the 128 cliff and halved residency (occupancy 9%).
template <int COND>
__global__ __launch_bounds__(256, 4) void k_gemm_qkv(
        const unsigned short* __restrict__ A, const unsigned short* __restrict__ Bt,
        const float* __restrict__ ct, const float* __restrict__ qn,
        const float* __restrict__ kn, unsigned short* __restrict__ qb,
        unsigned short* __restrict__ kb, unsigned short* __restrict__ vT) {
    constexpr int M = COND ? 616 : 8192;
    constexpr int K = COND ? 768 : 512;
    constexpr int nOff = COND ? 512 : 0;
    __shared__ __align__(1024) char SMEM[34816];  // loop: As/Bs 16K+16K; epi: stage[128][136]
    unsigned short* As = (unsigned short*)SMEM;
    unsigned short* Bs = (unsigned short*)(SMEM + 16384);
    int tid = threadIdx.x;
    int w = tid >> 6, l = tid & 63, lg = l >> 4, ll = l & 15;
    int wr = w >> 1, wc = w & 1;
    int m0 = blockIdx.y * 128, n0 = nOff + blockIdx.x * 128;
    int r8 = l >> 3, c16 = (l & 7) * 16;
    f32x4 acc[4][4] = {};
    const char* Ac = (const char*)A;
    const char* Bc = (const char*)Bt;
    constexpr size_t rowBytes = (size_t)K * 2;
    for (int k0 = 0; k0 < K; k0 += 64) {
        __syncthreads();
        #pragma unroll
        for (int i = 0; i < 8; ++i) {
            int c = w * 8 + i;
            if (c < 16) {
                int row = c * 8 + r8;
                int off = c16 ^ ((row & 7) << 4);
                int ar = m0 + row;
                if (ar > M - 1) ar = M - 1;
                gload16(Ac + (size_t)ar * rowBytes + k0 * 2 + off, (char*)As + c * 1024);
            } else {
                int cc = c - 16;
                int row = cc * 8 + r8;
                int off = c16 ^ ((row & 7) << 4);
                gload16(Bc + (size_t)(n0 + row) * rowBytes + k0 * 2 + off, (char*)Bs + cc * 1024);
            }
        }
        __syncthreads();
        #pragma unroll
        for (int ks = 0; ks < 2; ++ks) {
            bhalf8 af[4], bf[4];
            #pragma unroll
            for (int mi = 0; mi < 4; ++mi)
                af[mi] = *(const bhalf8*)((char*)As + swz((wr * 64 + mi * 16 + ll) * 128 + ks * 64 + lg * 16));
            #pragma unroll
            for (int ni = 0; ni < 4; ++ni)
                bf[ni] = *(const bhalf8*)((char*)Bs + swz((wc * 64 + ni * 16 + ll) * 128 + ks * 64 + lg * 16));
            __builtin_amdgcn_s_setprio(1);
            #pragma unroll
            for (int mi = 0; mi < 4; ++mi)
                #pragma unroll
                for (int ni = 0; ni < 4; ++ni)
                    acc[mi][ni] = __builtin_amdgcn_mfma_f32_16x16x32_bf16(af[mi], bf[ni], acc[mi][ni], 0, 0, 0);
            __builtin_amdgcn_s_setprio(0);
        }
    }
    int type = n0 >> 9;  // 0 q, 1 k, >=2 v
    const float2* ct2 = (const float2*)ct;

    if (type >= 2) {  // ---- V: direct transposed bf16 writes ----
        int hd = (n0 - 1024 + wc * 64) >> 6;
        #pragma unroll
        for (int ni = 0; ni < 4; ++ni) {
            int d = ni * 16 + ll;
            #pragma unroll
            for (int mi = 0; mi < 4; ++mi) {
                int rowL = m0 + wr * 64 + mi * 16 + 4 * lg;
                if (COND == 0) {
                    int b = rowL >> 10, t = rowL & 1023;
                    uint2 pk = {cvtpk(acc[mi][ni][0], acc[mi][ni][1]),
                                cvtpk(acc[mi][ni][2], acc[mi][ni][3])};
                    *(uint2*)&vT[((size_t)(b * 8 + hd) * 64 + d) * VSTRIDE + t] = pk;
                } else {
                    #pragma unroll
                    for (int r = 0; r < 4; ++r) {
                        int row = rowL + r;
                        if (row < M) {
                            int b = row / 77, s = row - b * 77;
                            vT[((size_t)(b * 8 + hd) * 64 + d) * VSTRIDE + 1024 + s] =
                                f2bf(acc[mi][ni][r]);
                        }
                    }
                }
            }
        }
        return;
    }
    // ---- Q/K: RoPE + RMSNorm + scale, then LDS-transpose for coalesced stores ----
    const float* wnt = (type == 0) ? qn : kn;
    float wn[4];
    int jj[4];
    #pragma unroll
    for (int ni = 0; ni < 4; ++ni) {
        wn[ni] = wnt[ni * 16 + ll];
        jj[ni] = (ni * 16 + ll) >> 1;
    }
    float sgn = (ll & 1) ? 1.f : -1.f;
    #pragma unroll
    for (int mi = 0; mi < 4; ++mi) {
        int rowL = m0 + wr * 64 + mi * 16 + 4 * lg;
        int tt[4];
        #pragma unroll
        for (int r = 0; r < 4; ++r) {
            if (COND == 0) tt[r] = (rowL + r) & 1023;
            else {
                int row = rowL + r;
                if (row > M - 1) row = M - 1;
                int b = row / 77;
                tt[r] = 1024 + (row - b * 77);
            }
        }
        #pragma unroll
        for (int ni = 0; ni < 4; ++ni) {
            f32x4 a = acc[mi][ni], p;
            #pragma unroll
            for (int r = 0; r < 4; ++r) p[r] = __shfl_xor(a[r], 1);
            #pragma unroll
            for (int r = 0; r < 4; ++r) {
                float2 cs = ct2[tt[r] * 32 + jj[ni]];
                a[r] = fmaf(sgn * p[r], cs.y, a[r] * cs.x);
            }
            acc[mi][ni] = a;
        }
        f32x4 ss = {};
        #pragma unroll
        for (int ni = 0; ni < 4; ++ni)
            #pragma unroll
            for (int r = 0; r < 4; ++r) ss[r] = fmaf(acc[mi][ni][r], acc[mi][ni][r], ss[r]);
        #pragma unroll
        for (int msk = 1; msk < 16; msk <<= 1)
            #pragma unroll
            for (int r = 0; r < 4; ++r) ss[r] += __shfl_xor(ss[r], msk);
        f32x4 ri;
        #pragma unroll
        for (int r = 0; r < 4; ++r) {
            ri[r] = rsqrtf(ss[r] * (1.0f / 64.f) + 1.1920929e-07f);
            if (type == 0) ri[r] *= 0.18033688011112042f;  // 0.125 * log2(e)
        }
        #pragma unroll
        for (int ni = 0; ni < 4; ++ni)
            #pragma unroll
            for (int r = 0; r < 4; ++r) acc[mi][ni][r] *= ri[r] * wn[ni];
    }
    __syncthreads();
    unsigned short* stg = (unsigned short*)SMEM;  // [128][136]
    #pragma unroll
    for (int mi = 0; mi < 4; ++mi)
        #pragma unroll
        for (int ni = 0; ni < 4; ++ni) {
            int colL = wc * 64 + ni * 16 + ll;
            int rowL = wr * 64 + mi * 16 + 4 * lg;
            #pragma unroll
            for (int r = 0; r < 4; ++r)
                stg[(rowL + r) * 136 + colL] = f2bf(acc[mi][ni][r]);
        }
    __syncthreads();
    int rowO = tid >> 1, half = tid & 1;
    int rowG = m0 + rowO;
    if (COND == 1 && rowG >= M) return;
    int ch0 = n0 + half * 64;
    int b, t;
    if (COND == 0) { b = rowG >> 10; t = rowG & 1023; }
    else { b = rowG / 77; t = 1024 + (rowG - b * 77); }
    unsigned short* dst;
    if (type == 0) dst = qb + ((size_t)(b * 8 + (ch0 >> 6)) * HWN + t) * 64;
    else dst = kb + ((size_t)(b * 8 + ((ch0 - 512) >> 6)) * TTOT + t) * 64;
    #pragma unroll
    for (int i = 0; i < 8; ++i)
        *(bhalf8*)&dst[i * 8] = *(const bhalf8*)&stg[rowO * 136 + half * 64 + i * 8];
}

// -------- attn v8: no-shift exp2 softmax, MFMA-accumulated L, double-buffered K/V --------
// LDS 40KB: buf0 K[0,8K) V[8K,16K); buf1 K[16K,24K) V[24K,32K); P [32K,40K).
__global__ __launch_bounds__(256) void k_attn_v8(const unsigned short* __restrict__ qb,
        const unsigned short* __restrict__ kbuf, const unsigned short* __restrict__ vT,
        unsigned short* __restrict__ ob) {
    __shared__ __align__(1024) char smc[40960];
    int f = blockIdx.x;
    int xcd = f & 7, n = f >> 3;
    int q0 = (n & 15) * 64;
    int bh = ((n >> 4) << 3) | xcd;
    int tid = threadIdx.x;
    int w = tid >> 6, l = tid & 63, lg = l >> 4, ll = l & 15;
    int r8 = l >> 3, c16 = (l & 7) * 16;
    bhalf8 qf[2];
    {
        const unsigned short* qbase = qb + ((size_t)bh * HWN + q0 + w * 16) * 64;
        #pragma unroll
        for (int ks = 0; ks < 2; ++ks)
            qf[ks] = *(const bhalf8*)&qbase[ll * 64 + ks * 32 + lg * 8];
    }
    bhalf8 onesf;
    #pragma unroll
    for (int i = 0; i < 8; ++i) onesf[i] = (short)0x3F80;  // bf16 1.0
    f32x4 accO[4] = {};   // O^T[d=d4*16+4lg+r][q=ll]
    f32x4 Lacc = {};      // all 4 rows = sum_k P[k][q=ll]
    const char* kgl = (const char*)kbuf + (size_t)bh * TTOT * 128;
    const char* vgl = (const char*)vT + (size_t)bh * 64 * (VSTRIDE * 2);
    char* pw = smc + 32768 + w * 2048 + ll * 128;
    int pswz = (ll & 7) << 4;

    auto stage = [&](int kt, int bsel) {
        char* base = smc + bsel * 16384;
        #pragma unroll
        for (int i = 0; i < 4; ++i) {
            int c = w * 4 + i;
            if (c < 8) {  // K chunk: rows = keys
                int row = c * 8 + r8;
                int t = kt * 64 + row;
                if (t > TTOT - 1) t = TTOT - 1;  // clamped rows are softmax-masked
                gload16(kgl + (size_t)t * 128 + (c16 ^ ((row & 7) << 4)), base + c * 1024);
            } else {      // V^T chunk: rows = d
                int row = (c - 8) * 8 + r8;
                gload16(vgl + (size_t)row * (VSTRIDE * 2) + kt * 128 + (c16 ^ ((row & 7) << 4)),
                        base + 8192 + (c - 8) * 1024);
            }
        }
    };
    stage(0, 0);
    __syncthreads();  // tile 0 landed
    for (int kt = 0; kt < 18; ++kt) {
        int cur = kt & 1;
        if (kt < 17) stage(kt + 1, cur ^ 1);  // issue next tile; latency hides under compute
        char* kl = smc + cur * 16384;
        char* vl = kl + 8192;
        // S^T = K x Q
        f32x4 s[4] = {};
        __builtin_amdgcn_s_setprio(1);
        #pragma unroll
        for (int ks = 0; ks < 2; ++ks) {
            bhalf8 kf[4];
            #pragma unroll
            for (int k4 = 0; k4 < 4; ++k4)
                kf[k4] = *(const bhalf8*)(kl + swz((k4 * 16 + ll) * 128 + ks * 64 + lg * 16));
            #pragma unroll
            for (int k4 = 0; k4 < 4; ++k4)
                s[k4] = __builtin_amdgcn_mfma_f32_16x16x32_bf16(kf[k4], qf[ks], s[k4], 0, 0, 0);
        }
        __builtin_amdgcn_s_setprio(0);
        if (kt == 17) {  // mask tail keys (key index lane-local: k4*16 + 4lg + r)
            int kb0 = kt * 64 + 4 * lg;
            #pragma unroll
            for (int k4 = 0; k4 < 4; ++k4)
                #pragma unroll
                for (int r = 0; r < 4; ++r)
                    if (kb0 + k4 * 16 + r >= TTOT) s[k4][r] = -1e30f;
        }
        // softmax, no shift: P = exp2(s); uniform scale cancels in O=PV/L.
        #pragma unroll
        for (int k4 = 0; k4 < 4; ++k4) {
            float p0 = exp2f(s[k4][0]), p1 = exp2f(s[k4][1]);
            float p2 = exp2f(s[k4][2]), p3 = exp2f(s[k4][3]);
            uint2 pk = {cvtpk(p0, p1), cvtpk(p2, p3)};
            *(uint2*)(pw + ((k4 * 32 + lg * 8) ^ pswz)) = pk;
        }
        // O^T += V^T x P ; L += ones x P
        __builtin_amdgcn_s_setprio(1);
        #pragma unroll
        for (int ks = 0; ks < 2; ++ks) {
            bhalf8 vf[4];
            #pragma unroll
            for (int d4 = 0; d4 < 4; ++d4)
                vf[d4] = *(const bhalf8*)(vl + swz((d4 * 16 + ll) * 128 + ks * 64 + lg * 16));
            bhalf8 pf = *(const bhalf8*)(smc + 32768 + w * 2048 + swz(ll * 128 + ks * 64 + lg * 16));
            Lacc = __builtin_amdgcn_mfma_f32_16x16x32_bf16(onesf, pf, Lacc, 0, 0, 0);
            #pragma unroll
            for (int d4 = 0; d4 < 4; ++d4)
                accO[d4] = __builtin_amdgcn_mfma_f32_16x16x32_bf16(vf[d4], pf, accO[d4], 0, 0, 0);
        }
        __builtin_amdgcn_s_setprio(0);
        __syncthreads();  // next-tile loads landed; all waves done with cur buffers
    }
    // epilogue: /L, transpose O^T -> [q][d] via LDS, coalesced stores
    {
        float inv = 1.0f / Lacc[0];
        int orow = w * 16 + ll;
        char* po = smc + orow * 128;
        int oswz = (orow & 7) << 4;
        #pragma unroll
        for (int d4 = 0; d4 < 4; ++d4) {
            uint2 pk = {cvtpk(accO[d4][0] * inv, accO[d4][1] * inv),
                        cvtpk(accO[d4][2] * inv, accO[d4][3] * inv)};
            *(uint2*)(po + ((d4 * 32 + lg * 8) ^ oswz)) = pk;
        }
    }
    __syncthreads();
    int b = bh >> 3, h = bh & 7;
    int row = tid >> 2, seg = tid & 3;
    bhalf8 v0 = *(const bhalf8*)(smc + swz(row * 128 + seg * 32));
    bhalf8 v1 = *(const bhalf8*)(smc + swz(row * 128 + seg * 32 + 16));
    unsigned short* dst = ob + ((size_t)(b * HWN + q0 + row)) * CH + h * 64 + seg * 16;
    *(bhalf8*)&dst[0] = v0;
    *(bhalf8*)&dst[8] = v1;
}

extern "C" void kernel_launch(void* const* d_in, const int* in_sizes, int n_in,
                              void* d_out, int out_size, void* d_ws, size_t ws_size,
                              hipStream_t stream) {
    const float* x     = (const float*)d_in[0];
    const float* cond  = (const float*)d_in[1];
    const float* femb  = (const float*)d_in[2];
    const float* mod_w = (const float*)d_in[3];
    const float* mod_b = (const float*)d_in[4];
    const float* n1s   = (const float*)d_in[5];
    const float* n2s   = (const float*)d_in[6];
    const float* qkvsw = (const float*)d_in[7];
    const float* qkvcw = (const float*)d_in[8];
    const float* ropef = (const float*)d_in[9];
    const float* qn    = (const float*)d_in[10];
    const float* kn    = (const float*)d_in[11];
    const float* outw  = (const float*)d_in[12];
    const float* outb  = (const float*)d_in[13];
    const float* w1    = (const float*)d_in[14];
    const float* b1    = (const float*)d_in[15];
    const float* w2    = (const float*)d_in[16];
    const float* b2    = (const float*)d_in[17];
    float* out = (float*)d_out;
    char* W = (char*)d_ws;

    // byte layout (~95.5 MB peak)
    unsigned short* wqs_b = (unsigned short*)(W + 0);         // 1536x512
    unsigned short* wqc_b = (unsigned short*)(W + 1572864);   // 1536x768
    unsigned short* wo_b  = (unsigned short*)(W + 3932160);   // 512x512
    unsigned short* w1_b  = (unsigned short*)(W + 4456448);   // 2048x512
    unsigned short* w2_b  = (unsigned short*)(W + 6553600);   // 512x2048
    unsigned short* condb = (unsigned short*)(W + 8650752);   // 616x768
    float* mod            = (float*)(W + 9596928);            // 8x3072
    float* ct             = (float*)(W + 9695232);            // 1101x32 float2
    unsigned short* hmod  = (unsigned short*)(W + 9977088);   // 8192x512 bf16
    unsigned short* obuf  = hmod;                             // overlays hmod (dead post-qkv)
    unsigned short* qbuf  = (unsigned short*)(W + 18365696);  // 64x1024x64 bf16
    unsigned short* kbuf  = (unsigned short*)(W + 26754304);  // 64x1101x64 bf16
    unsigned short* vTb   = (unsigned short*)(W + 35772672);  // 64x64x1152 bf16
    unsigned short* h2    = vTb;                              // overlays vT (dead post-attn)
    unsigned short* mbuf  = (unsigned short*)(W + 45209856);  // 8192x2048 bf16
    float* x1             = (float*)(W + 78764288);           // 8x512x1024 f32
    float* sebuf          = (float*)(W + 45209920);           // 8x768 f32 (pre-MLP1 liveness)

    PrepArgs pa;
    pa.src[0] = qkvsw; pa.dst[0] = wqs_b; pa.n[0] = 1536 * 512;
    pa.src[1] = qkvcw; pa.dst[1] = wqc_b; pa.n[1] = 1536 * 768;
    pa.src[2] = outw;  pa.dst[2] = wo_b;  pa.n[2] = 512 * 512;
    pa.src[3] = w1;    pa.dst[3] = w1_b;  pa.n[3] = 2048 * 512;
    pa.src[4] = w2;    pa.dst[4] = w2_b;  pa.n[4] = 512 * 2048;
    pa.src[5] = cond;  pa.dst[5] = condb; pa.n[5] = 616 * 768;
    pa.freqs = ropef; pa.ct = ct;
    pa.emb = femb; pa.mbias = mod_b; pa.mod = mod; pa.se = sebuf;
    k_prep<<<dim3(1152, 8), 256, 0, stream>>>(pa);
    k_mod<<<dim3(12, 8, 8), 256, 0, stream>>>(sebuf, mod_w, mod);

    k_rms2d_mod_t<<<dim3(16, BATCH), 256, 0, stream>>>(x, n1s, mod, 0, 512, hmod);
    // qkv (spatial): fused RoPE/RMS/V^T epilogue
    k_gemm_qkv<0><<<dim3(12, 64), 256, 0, stream>>>(hmod, wqs_b, ct, qn, kn,
                                                    qbuf, kbuf, vTb);
    // qkv (cond): k/v tiles only (nOff=512)
    k_gemm_qkv<1><<<dim3(8, 5), 256, 0, stream>>>(condb, wqc_b, ct, qn, kn,
                                                  qbuf, kbuf, vTb);
    k_attn_v8<<<dim3(1024), 256, 0, stream>>>(qbuf, kbuf, vTb, obuf);
    // out-proj: x1 = x + g1*(obuf @ Wo^T + outb)  (channel-major f32), 128x64 2-phase
    k_gemm_mfma<1, 128, 64><<<dim3(8, 64), 256, 0, stream>>>(
        obuf, wo_b, x1, 8192, 512, 512, outb, mod + 2 * 512, x);
    k_rms2d_mod_t<<<dim3(16, BATCH), 256, 0, stream>>>(x1, n2s, mod, 3 * 512, 4 * 512, h2);
    // MLP1 + fast gelu -> bf16 [8192,2048], 128x128 2-phase (1024 blocks)
    k_gemm_mfma<2, 128, 128><<<dim3(16, 64), 256, 0, stream>>>(
        h2, w1_b, mbuf, 8192, 2048, 512, b1, nullptr, nullptr);
    // MLP2 + gate + residual -> d_out (channel-major f32), 128x64 2-phase
    k_gemm_mfma<1, 128, 64><<<dim3(8, 64), 256, 0, stream>>>(
        mbuf, w2_b, out, 8192, 512, 2048, b2, mod + 5 * 512, x1);
}

// Round 13
// 265.573 us; speedup vs baseline: 1.3049x; 1.3049x over previous
//
#include <hip/hip_runtime.h>

// FluxUNet fused block — round 13: revert r12's launch_bounds (spilled);
// manual register trim in qkv epilogue (no hoisted tables) to get <=128 VGPR.
// B=8, C=512, HW=1024, S=77, E=768, NH=8, HD=64, HID=2048, T=1101.
constexpr int BATCH = 8, CH = 512, HWN = 1024, SEQ = 77, EMB = 768;
constexpr int NHEAD = 8, HDIM = 64, HIDDEN = 2048, TTOT = 1101;
constexpr int VSTRIDE = 1152;  // padded t-stride for transposed V

typedef short bhalf8 __attribute__((ext_vector_type(8)));
typedef float f32x4 __attribute__((ext_vector_type(4)));

__device__ __forceinline__ unsigned short f2bf(float f) {
    unsigned u = __builtin_bit_cast(unsigned, f);
    unsigned r = (u + 0x7fffu + ((u >> 16) & 1u)) >> 16;
    return (unsigned short)r;
}
__device__ __forceinline__ unsigned cvtpk(float a, float b) {
    unsigned r;
    asm("v_cvt_pk_bf16_f32 %0, %1, %2" : "=v"(r) : "v"(a), "v"(b));
    return r;
}
// gelu_tanh via identity 0.5(1+tanh(u)) = 1 - 1/(e^{2u}+1); e^{2u} = 2^{2u*log2e}.
__device__ __forceinline__ float gelu_fast(float v) {
    float c = v * v * v;
    float z = fmaf(v, 2.3022082f, c * 0.10294324f);
    float e = exp2f(z) + 1.0f;
    float r;
    asm("v_rcp_f32 %0, %1" : "=v"(r) : "v"(e));
    return v - v * r;
}
// XOR-swizzle on a 128B-row-stride LDS tile (region base must be 1024B-aligned).
__device__ __forceinline__ int swz(int b) { return b ^ ((b >> 3) & 0x70); }

// async global->LDS 16B: LDS dest = wave-uniform base + lane*16.
__device__ __forceinline__ void gload16(const void* g, void* l) {
    __builtin_amdgcn_global_load_lds(
        (const __attribute__((address_space(1))) unsigned int*)g,
        (__attribute__((address_space(3))) unsigned int*)l, 16, 0, 0);
}

// ---------- merged prep: casts (y<6), rope table (y==6),
// ----------             y==7: mod bias-init / silu(emb) ----------
struct PrepArgs {
    const float* src[6];
    unsigned short* dst[6];
    int n[6];
    const float* freqs;
    float* ct;
    const float* emb;
    const float* mbias;
    float* mod;
    float* se;       // silu(emb) [8][768]
};
__global__ void k_prep(PrepArgs a) {
    int y = blockIdx.y;
    int bx = blockIdx.x;
    int tid = threadIdx.x;
    if (y < 6) {
        int i = (bx * 256 + tid) * 4;
        if (i >= a.n[y]) return;
        float4 v = *(const float4*)&a.src[y][i];
        ushort4 o = {f2bf(v.x), f2bf(v.y), f2bf(v.z), f2bf(v.w)};
        *(ushort4*)&a.dst[y][i] = o;
    } else if (y == 6) {
        int i = bx * 256 + tid;
        if (i >= TTOT * 32) return;
        int t = i >> 5, j = i & 31;
        float ang;
        if (t < HWN) {
            ang = (float)(t >> 5) * a.freqs[2 * j] + (float)(t & 31) * a.freqs[2 * j + 1];
        } else {
            float inv = expf(-(float)j * (9.210340371976184f / 32.0f));
            ang = (float)(t - HWN) * inv;
        }
        a.ct[i * 2] = cosf(ang);
        a.ct[i * 2 + 1] = sinf(ang);
    } else {
        if (bx < 24) {            // mod = bias (atomic partials land on top)
            int i = bx * 1024 + tid * 4;           // i = b*3072 + j, j%4==0
            int j = i - (i / (6 * CH)) * (6 * CH);
            *(float4*)&a.mod[i] = *(const float4*)&a.mbias[j];
        } else if (bx >= 32 && bx < 38) {  // silu(final_emb) -> se [6144 floats]
            int i = (bx - 32) * 1024 + tid * 4;
            float4 v = *(const float4*)&a.emb[i];
            float4 o;
            o.x = v.x / (1.0f + expf(-v.x));
            o.y = v.y / (1.0f + expf(-v.y));
            o.z = v.z / (1.0f + expf(-v.z));
            o.w = v.w / (1.0f + expf(-v.w));
            *(float4*)&a.se[i] = o;
        }
    }
}

// ---------- modulation partials: mod[b][j] += sum_{e in chunk} se[b][e] * w[e][j] ----------
__global__ __launch_bounds__(256) void k_mod(const float* __restrict__ se,
        const float* __restrict__ w, float* __restrict__ mod) {
    int jb = blockIdx.x, b = blockIdx.y, ec = blockIdx.z;
    int j = jb * 256 + threadIdx.x;
    const float* sb = se + b * EMB + ec * 96;
    const float* wb = w + (size_t)(ec * 96) * (6 * CH) + j;
    float acc = 0.f;
    #pragma unroll 8
    for (int e = 0; e < 96; ++e) acc = fmaf(sb[e], wb[(size_t)e * (6 * CH)], acc);
    atomicAdd(&mod[b * (6 * CH) + j], acc);
}

// ------- RMSNorm(channel) + adaLN modulate + transpose -> bf16 token-major -------
__global__ __launch_bounds__(256) void k_rms2d_mod_t(const float* __restrict__ xin,
        const float* __restrict__ sw, const float* __restrict__ mod, int shoff, int scoff,
        unsigned short* __restrict__ outp) {
    __shared__ float part[4][64];
    __shared__ float rinv[64];
    int b = blockIdx.y;
    int n0 = blockIdx.x * 64;
    int tid = threadIdx.x;
    const float* xb = xin + (size_t)b * CH * HWN;
    {
        int n = n0 + (tid & 63);
        int cg = tid >> 6;
        float ss = 0.f;
        #pragma unroll 8
        for (int c = cg * 128; c < cg * 128 + 128; ++c) {
            float v = xb[(size_t)c * HWN + n];
            ss = fmaf(v, v, ss);
        }
        part[cg][tid & 63] = ss;
    }
    __syncthreads();
    if (tid < 64) {
        float s = part[0][tid] + part[1][tid] + part[2][tid] + part[3][tid];
        rinv[tid] = rsqrtf(s * (1.0f / CH) + 1e-6f);
    }
    __syncthreads();
    int n = n0 + (tid >> 2);
    int cq = tid & 3;
    float r = rinv[tid >> 2];
    const float* mb = mod + b * (6 * CH);
    unsigned short* orow = outp + ((size_t)(b * HWN + n)) * CH;
    for (int jc = 0; jc < 16; ++jc) {
        int c = cq * 128 + jc * 8;
        bhalf8 o;
        #pragma unroll
        for (int u = 0; u < 8; ++u) {
            int cc = c + u;
            float v = xb[(size_t)cc * HWN + n];
            float y = v * r * sw[cc] * (1.0f + mb[scoff + cc]) + mb[shoff + cc];
            o[u] = (short)f2bf(y);
        }
        *(bhalf8*)&orow[c] = o;
    }
}

// ------- bf16 MFMA GEMM, 2-phase double-buffered (prefetch t+1 before compute t) -------
// A [M][K], Bt [N][K] bf16 row-major. K%64==0, N%BN==0, M row-clamped.
// EPI=1: f32 channel-major residual+gate (BM=128).  EPI=2: bf16 gelu token-major.
template <int EPI, int BM, int BN>
__global__ __launch_bounds__(256) void k_gemm_mfma(
        const unsigned short* __restrict__ A, const unsigned short* __restrict__ Bt,
        void* __restrict__ OutV, int M, int N, int K,
        const float* __restrict__ bias, const float* __restrict__ gate,
        const float* __restrict__ res) {
    constexpr int WM = BM / 2, WN = BN / 2;
    constexpr int MI = WM / 16, NI = WN / 16;
    constexpr int CA = BM / 8, CB = BN / 8, CW = (CA + CB) / 4;
    constexpr int BUF = (BM + BN) * 128;
    __shared__ __align__(1024) char SM[2 * BUF];
    int tid = threadIdx.x;
    int w = tid >> 6, l = tid & 63, lg = l >> 4, ll = l & 15;
    int wr = w >> 1, wc = w & 1;
    int m0 = blockIdx.y * BM, n0 = blockIdx.x * BN;
    int r8 = l >> 3, c16 = (l & 7) * 16;
    f32x4 acc[MI][NI] = {};
    const char* Ac = (const char*)A;
    const char* Bc = (const char*)Bt;
    size_t rowBytes = (size_t)K * 2;
    int nt = K >> 6;

    auto stage = [&](int t, int bsel) {
        char* As = SM + bsel * BUF;
        char* Bs = As + BM * 128;
        int k0 = t * 64;
        #pragma unroll
        for (int i = 0; i < CW; ++i) {
            int c = w * CW + i;
            if (c < CA) {
                int row = c * 8 + r8;
                int off = c16 ^ ((row & 7) << 4);
                int ar = m0 + row;
                if (ar > M - 1) ar = M - 1;
                gload16(Ac + (size_t)ar * rowBytes + k0 * 2 + off, As + c * 1024);
            } else {
                int cc = c - CA;
                int row = cc * 8 + r8;
                int off = c16 ^ ((row & 7) << 4);
                gload16(Bc + (size_t)(n0 + row) * rowBytes + k0 * 2 + off, Bs + cc * 1024);
            }
        }
    };
    stage(0, 0);
    __syncthreads();  // tile 0 landed
    int cur = 0;
    for (int t = 0; t < nt; ++t) {
        if (t + 1 < nt) stage(t + 1, cur ^ 1);  // latency hides under compute of tile t
        char* As = SM + cur * BUF;
        char* Bs = As + BM * 128;
        #pragma unroll
        for (int ks = 0; ks < 2; ++ks) {
            bhalf8 af[MI], bf[NI];
            #pragma unroll
            for (int mi = 0; mi < MI; ++mi)
                af[mi] = *(const bhalf8*)(As + swz((wr * WM + mi * 16 + ll) * 128 + ks * 64 + lg * 16));
            #pragma unroll
            for (int ni = 0; ni < NI; ++ni)
                bf[ni] = *(const bhalf8*)(Bs + swz((wc * WN + ni * 16 + ll) * 128 + ks * 64 + lg * 16));
            __builtin_amdgcn_s_setprio(1);
            #pragma unroll
            for (int mi = 0; mi < MI; ++mi)
                #pragma unroll
                for (int ni = 0; ni < NI; ++ni)
                    acc[mi][ni] = __builtin_amdgcn_mfma_f32_16x16x32_bf16(af[mi], bf[ni], acc[mi][ni], 0, 0, 0);
            __builtin_amdgcn_s_setprio(0);
        }
        __syncthreads();  // next tile landed; all waves done with cur buffers
        cur ^= 1;
    }
    if (EPI == 2) {
        unsigned short* Out = (unsigned short*)OutV;
        #pragma unroll
        for (int mi = 0; mi < MI; ++mi)
            #pragma unroll
            for (int ni = 0; ni < NI; ++ni) {
                int col = n0 + wc * WN + ni * 16 + ll;
                float bv = bias[col];
                #pragma unroll
                for (int r = 0; r < 4; ++r) {
                    int mrow = m0 + wr * WM + mi * 16 + 4 * lg + r;
                    Out[(size_t)mrow * N + col] = f2bf(gelu_fast(acc[mi][ni][r] + bv));
                }
            }
    } else {
        float* Out = (float*)OutV;
        int bidx = m0 >> 10;
        int hw0 = m0 & 1023;
        const float* resb = res + (size_t)bidx * N * HWN;
        float* outb_ = Out + (size_t)bidx * N * HWN;
        #pragma unroll
        for (int ni = 0; ni < NI; ++ni) {
            int ch = n0 + wc * WN + ni * 16 + ll;
            float g = gate[bidx * (6 * CH) + ch];
            float bv = bias[ch];
            #pragma unroll
            for (int mi = 0; mi < MI; ++mi) {
                int t = hw0 + wr * WM + mi * 16 + 4 * lg;
                float4 r4 = *(const float4*)&resb[(size_t)ch * HWN + t];
                f32x4 a = acc[mi][ni];
                float4 o;
                o.x = r4.x + g * (a[0] + bv);
                o.y = r4.y + g * (a[1] + bv);
                o.z = r4.z + g * (a[2] + bv);
                o.w = r4.w + g * (a[3] + bv);
                *(float4*)&outb_[(size_t)ch * HWN + t] = o;
            }
        }
    }
}

// ------- qkv GEMM with fused RoPE + qk-RMSNorm + head-split + V-transpose -------
// COND=0: A=hmod [8192][512], grid (12,64), nOff=0.
// COND=1: A=condb [616][768], grid (8,5), nOff=512.  All shapes compile-time.
// Epilogue deliberately register-lean: no hoisted tables (r11 hit 132 VGPR ->
// crossed the 128 occupancy cliff; r12's forced bound spilled).
template <int COND>
__global__ __launch_bounds__(256) void k_gemm_qkv(
        const unsigned short* __restrict__ A, const unsigned short* __restrict__ Bt,
        const float* __restrict__ ct, const float* __restrict__ qn,
        const float* __restrict__ kn, unsigned short* __restrict__ qb,
        unsigned short* __restrict__ kb, unsigned short* __restrict__ vT) {
    constexpr int M = COND ? 616 : 8192;
    constexpr int K = COND ? 768 : 512;
    constexpr int nOff = COND ? 512 : 0;
    __shared__ __align__(1024) char SMEM[34816];  // loop: As/Bs 16K+16K; epi: stage[128][136]
    unsigned short* As = (unsigned short*)SMEM;
    unsigned short* Bs = (unsigned short*)(SMEM + 16384);
    int tid = threadIdx.x;
    int w = tid >> 6, l = tid & 63, lg = l >> 4, ll = l & 15;
    int wr = w >> 1, wc = w & 1;
    int m0 = blockIdx.y * 128, n0 = nOff + blockIdx.x * 128;
    int r8 = l >> 3, c16 = (l & 7) * 16;
    f32x4 acc[4][4] = {};
    const char* Ac = (const char*)A;
    const char* Bc = (const char*)Bt;
    constexpr size_t rowBytes = (size_t)K * 2;
    for (int k0 = 0; k0 < K; k0 += 64) {
        __syncthreads();
        #pragma unroll
        for (int i = 0; i < 8; ++i) {
            int c = w * 8 + i;
            if (c < 16) {
                int row = c * 8 + r8;
                int off = c16 ^ ((row & 7) << 4);
                int ar = m0 + row;
                if (ar > M - 1) ar = M - 1;
                gload16(Ac + (size_t)ar * rowBytes + k0 * 2 + off, (char*)As + c * 1024);
            } else {
                int cc = c - 16;
                int row = cc * 8 + r8;
                int off = c16 ^ ((row & 7) << 4);
                gload16(Bc + (size_t)(n0 + row) * rowBytes + k0 * 2 + off, (char*)Bs + cc * 1024);
            }
        }
        __syncthreads();
        #pragma unroll
        for (int ks = 0; ks < 2; ++ks) {
            bhalf8 af[4], bf[4];
            #pragma unroll
            for (int mi = 0; mi < 4; ++mi)
                af[mi] = *(const bhalf8*)((char*)As + swz((wr * 64 + mi * 16 + ll) * 128 + ks * 64 + lg * 16));
            #pragma unroll
            for (int ni = 0; ni < 4; ++ni)
                bf[ni] = *(const bhalf8*)((char*)Bs + swz((wc * 64 + ni * 16 + ll) * 128 + ks * 64 + lg * 16));
            __builtin_amdgcn_s_setprio(1);
            #pragma unroll
            for (int mi = 0; mi < 4; ++mi)
                #pragma unroll
                for (int ni = 0; ni < 4; ++ni)
                    acc[mi][ni] = __builtin_amdgcn_mfma_f32_16x16x32_bf16(af[mi], bf[ni], acc[mi][ni], 0, 0, 0);
            __builtin_amdgcn_s_setprio(0);
        }
    }
    int type = n0 >> 9;  // 0 q, 1 k, >=2 v
    const float2* ct2 = (const float2*)ct;

    if (type >= 2) {  // ---- V: direct transposed bf16 writes ----
        int hd = (n0 - 1024 + wc * 64) >> 6;
        #pragma unroll
        for (int ni = 0; ni < 4; ++ni) {
            int d = ni * 16 + ll;
            #pragma unroll
            for (int mi = 0; mi < 4; ++mi) {
                int rowL = m0 + wr * 64 + mi * 16 + 4 * lg;
                if (COND == 0) {
                    int b = rowL >> 10, t = rowL & 1023;
                    uint2 pk = {cvtpk(acc[mi][ni][0], acc[mi][ni][1]),
                                cvtpk(acc[mi][ni][2], acc[mi][ni][3])};
                    *(uint2*)&vT[((size_t)(b * 8 + hd) * 64 + d) * VSTRIDE + t] = pk;
                } else {
                    #pragma unroll
                    for (int r = 0; r < 4; ++r) {
                        int row = rowL + r;
                        if (row < M) {
                            int b = row / 77, s = row - b * 77;
                            vT[((size_t)(b * 8 + hd) * 64 + d) * VSTRIDE + 1024 + s] =
                                f2bf(acc[mi][ni][r]);
                        }
                    }
                }
            }
        }
        return;
    }
    // ---- Q/K: RoPE + RMSNorm + scale, then LDS-transpose for coalesced stores ----
    // No hoisted per-ni tables: everything recomputed per use to stay <=128 VGPR.
    const float* wnt = (type == 0) ? qn : kn;
    float wscale = (type == 0) ? 0.18033688011112042f : 1.0f;  // 0.125*log2e folded
    float sgn = (ll & 1) ? 1.f : -1.f;
    #pragma unroll
    for (int mi = 0; mi < 4; ++mi) {
        int rowL = m0 + wr * 64 + mi * 16 + 4 * lg;
        int tt[4];
        #pragma unroll
        for (int r = 0; r < 4; ++r) {
            if (COND == 0) tt[r] = (rowL + r) & 1023;
            else {
                int row = rowL + r;
                if (row > M - 1) row = M - 1;
                int b = row / 77;
                tt[r] = 1024 + (row - b * 77);
            }
        }
        #pragma unroll
        for (int ni = 0; ni < 4; ++ni) {
            int jjv = (ni * 16 + ll) >> 1;
            f32x4 a = acc[mi][ni], p;
            #pragma unroll
            for (int r = 0; r < 4; ++r) p[r] = __shfl_xor(a[r], 1);
            #pragma unroll
            for (int r = 0; r < 4; ++r) {
                float2 cs = ct2[tt[r] * 32 + jjv];
                a[r] = fmaf(sgn * p[r], cs.y, a[r] * cs.x);
            }
            acc[mi][ni] = a;
        }
        f32x4 ss = {};
        #pragma unroll
        for (int ni = 0; ni < 4; ++ni)
            #pragma unroll
            for (int r = 0; r < 4; ++r) ss[r] = fmaf(acc[mi][ni][r], acc[mi][ni][r], ss[r]);
        #pragma unroll
        for (int msk = 1; msk < 16; msk <<= 1)
            #pragma unroll
            for (int r = 0; r < 4; ++r) ss[r] += __shfl_xor(ss[r], msk);
        #pragma unroll
        for (int r = 0; r < 4; ++r)
            ss[r] = rsqrtf(ss[r] * (1.0f / 64.f) + 1.1920929e-07f) * wscale;
        #pragma unroll
        for (int ni = 0; ni < 4; ++ni) {
            float wv = wnt[ni * 16 + ll];
            #pragma unroll
            for (int r = 0; r < 4; ++r) acc[mi][ni][r] *= ss[r] * wv;
        }
    }
    __syncthreads();
    unsigned short* stg = (unsigned short*)SMEM;  // [128][136]
    #pragma unroll
    for (int mi = 0; mi < 4; ++mi)
        #pragma unroll
        for (int ni = 0; ni < 4; ++ni) {
            int colL = wc * 64 + ni * 16 + ll;
            int rowL = wr * 64 + mi * 16 + 4 * lg;
            #pragma unroll
            for (int r = 0; r < 4; ++r)
                stg[(rowL + r) * 136 + colL] = f2bf(acc[mi][ni][r]);
        }
    __syncthreads();
    int rowO = tid >> 1, half = tid & 1;
    int rowG = m0 + rowO;
    if (COND == 1 && rowG >= M) return;
    int ch0 = n0 + half * 64;
    int b, t;
    if (COND == 0) { b = rowG >> 10; t = rowG & 1023; }
    else { b = rowG / 77; t = 1024 + (rowG - b * 77); }
    unsigned short* dst;
    if (type == 0) dst = qb + ((size_t)(b * 8 + (ch0 >> 6)) * HWN + t) * 64;
    else dst = kb + ((size_t)(b * 8 + ((ch0 - 512) >> 6)) * TTOT + t) * 64;
    #pragma unroll
    for (int i = 0; i < 8; ++i)
        *(bhalf8*)&dst[i * 8] = *(const bhalf8*)&stg[rowO * 136 + half * 64 + i * 8];
}

// -------- attn v8: no-shift exp2 softmax, MFMA-accumulated L, double-buffered K/V --------
// LDS 40KB: buf0 K[0,8K) V[8K,16K); buf1 K[16K,24K) V[24K,32K); P [32K,40K).
__global__ __launch_bounds__(256) void k_attn_v8(const unsigned short* __restrict__ qb,
        const unsigned short* __restrict__ kbuf, const unsigned short* __restrict__ vT,
        unsigned short* __restrict__ ob) {
    __shared__ __align__(1024) char smc[40960];
    int f = blockIdx.x;
    int xcd = f & 7, n = f >> 3;
    int q0 = (n & 15) * 64;
    int bh = ((n >> 4) << 3) | xcd;
    int tid = threadIdx.x;
    int w = tid >> 6, l = tid & 63, lg = l >> 4, ll = l & 15;
    int r8 = l >> 3, c16 = (l & 7) * 16;
    bhalf8 qf[2];
    {
        const unsigned short* qbase = qb + ((size_t)bh * HWN + q0 + w * 16) * 64;
        #pragma unroll
        for (int ks = 0; ks < 2; ++ks)
            qf[ks] = *(const bhalf8*)&qbase[ll * 64 + ks * 32 + lg * 8];
    }
    bhalf8 onesf;
    #pragma unroll
    for (int i = 0; i < 8; ++i) onesf[i] = (short)0x3F80;  // bf16 1.0
    f32x4 accO[4] = {};   // O^T[d=d4*16+4lg+r][q=ll]
    f32x4 Lacc = {};      // all 4 rows = sum_k P[k][q=ll]
    const char* kgl = (const char*)kbuf + (size_t)bh * TTOT * 128;
    const char* vgl = (const char*)vT + (size_t)bh * 64 * (VSTRIDE * 2);
    char* pw = smc + 32768 + w * 2048 + ll * 128;
    int pswz = (ll & 7) << 4;

    auto stage = [&](int kt, int bsel) {
        char* base = smc + bsel * 16384;
        #pragma unroll
        for (int i = 0; i < 4; ++i) {
            int c = w * 4 + i;
            if (c < 8) {  // K chunk: rows = keys
                int row = c * 8 + r8;
                int t = kt * 64 + row;
                if (t > TTOT - 1) t = TTOT - 1;  // clamped rows are softmax-masked
                gload16(kgl + (size_t)t * 128 + (c16 ^ ((row & 7) << 4)), base + c * 1024);
            } else {      // V^T chunk: rows = d
                int row = (c - 8) * 8 + r8;
                gload16(vgl + (size_t)row * (VSTRIDE * 2) + kt * 128 + (c16 ^ ((row & 7) << 4)),
                        base + 8192 + (c - 8) * 1024);
            }
        }
    };
    stage(0, 0);
    __syncthreads();  // tile 0 landed
    for (int kt = 0; kt < 18; ++kt) {
        int cur = kt & 1;
        if (kt < 17) stage(kt + 1, cur ^ 1);  // issue next tile; latency hides under compute
        char* kl = smc + cur * 16384;
        char* vl = kl + 8192;
        // S^T = K x Q
        f32x4 s[4] = {};
        __builtin_amdgcn_s_setprio(1);
        #pragma unroll
        for (int ks = 0; ks < 2; ++ks) {
            bhalf8 kf[4];
            #pragma unroll
            for (int k4 = 0; k4 < 4; ++k4)
                kf[k4] = *(const bhalf8*)(kl + swz((k4 * 16 + ll) * 128 + ks * 64 + lg * 16));
            #pragma unroll
            for (int k4 = 0; k4 < 4; ++k4)
                s[k4] = __builtin_amdgcn_mfma_f32_16x16x32_bf16(kf[k4], qf[ks], s[k4], 0, 0, 0);
        }
        __builtin_amdgcn_s_setprio(0);
        if (kt == 17) {  // mask tail keys (key index lane-local: k4*16 + 4lg + r)
            int kb0 = kt * 64 + 4 * lg;
            #pragma unroll
            for (int k4 = 0; k4 < 4; ++k4)
                #pragma unroll
                for (int r = 0; r < 4; ++r)
                    if (kb0 + k4 * 16 + r >= TTOT) s[k4][r] = -1e30f;
        }
        // softmax, no shift: P = exp2(s); uniform scale cancels in O=PV/L.
        #pragma unroll
        for (int k4 = 0; k4 < 4; ++k4) {
            float p0 = exp2f(s[k4][0]), p1 = exp2f(s[k4][1]);
            float p2 = exp2f(s[k4][2]), p3 = exp2f(s[k4][3]);
            uint2 pk = {cvtpk(p0, p1), cvtpk(p2, p3)};
            *(uint2*)(pw + ((k4 * 32 + lg * 8) ^ pswz)) = pk;
        }
        // O^T += V^T x P ; L += ones x P
        __builtin_amdgcn_s_setprio(1);
        #pragma unroll
        for (int ks = 0; ks < 2; ++ks) {
            bhalf8 vf[4];
            #pragma unroll
            for (int d4 = 0; d4 < 4; ++d4)
                vf[d4] = *(const bhalf8*)(vl + swz((d4 * 16 + ll) * 128 + ks * 64 + lg * 16));
            bhalf8 pf = *(const bhalf8*)(smc + 32768 + w * 2048 + swz(ll * 128 + ks * 64 + lg * 16));
            Lacc = __builtin_amdgcn_mfma_f32_16x16x32_bf16(onesf, pf, Lacc, 0, 0, 0);
            #pragma unroll
            for (int d4 = 0; d4 < 4; ++d4)
                accO[d4] = __builtin_amdgcn_mfma_f32_16x16x32_bf16(vf[d4], pf, accO[d4], 0, 0, 0);
        }
        __builtin_amdgcn_s_setprio(0);
        __syncthreads();  // next-tile loads landed; all waves done with cur buffers
    }
    // epilogue: /L, transpose O^T -> [q][d] via LDS, coalesced stores
    {
        float inv = 1.0f / Lacc[0];
        int orow = w * 16 + ll;
        char* po = smc + orow * 128;
        int oswz = (orow & 7) << 4;
        #pragma unroll
        for (int d4 = 0; d4 < 4; ++d4) {
            uint2 pk = {cvtpk(accO[d4][0] * inv, accO[d4][1] * inv),
                        cvtpk(accO[d4][2] * inv, accO[d4][3] * inv)};
            *(uint2*)(po + ((d4 * 32 + lg * 8) ^ oswz)) = pk;
        }
    }
    __syncthreads();
    int b = bh >> 3, h = bh & 7;
    int row = tid >> 2, seg = tid & 3;
    bhalf8 v0 = *(const bhalf8*)(smc + swz(row * 128 + seg * 32));
    bhalf8 v1 = *(const bhalf8*)(smc + swz(row * 128 + seg * 32 + 16));
    unsigned short* dst = ob + ((size_t)(b * HWN + q0 + row)) * CH + h * 64 + seg * 16;
    *(bhalf8*)&dst[0] = v0;
    *(bhalf8*)&dst[8] = v1;
}

extern "C" void kernel_launch(void* const* d_in, const int* in_sizes, int n_in,
                              void* d_out, int out_size, void* d_ws, size_t ws_size,
                              hipStream_t stream) {
    const float* x     = (const float*)d_in[0];
    const float* cond  = (const float*)d_in[1];
    const float* femb  = (const float*)d_in[2];
    const float* mod_w = (const float*)d_in[3];
    const float* mod_b = (const float*)d_in[4];
    const float* n1s   = (const float*)d_in[5];
    const float* n2s   = (const float*)d_in[6];
    const float* qkvsw = (const float*)d_in[7];
    const float* qkvcw = (const float*)d_in[8];
    const float* ropef = (const float*)d_in[9];
    const float* qn    = (const float*)d_in[10];
    const float* kn    = (const float*)d_in[11];
    const float* outw  = (const float*)d_in[12];
    const float* outb  = (const float*)d_in[13];
    const float* w1    = (const float*)d_in[14];
    const float* b1    = (const float*)d_in[15];
    const float* w2    = (const float*)d_in[16];
    const float* b2    = (const float*)d_in[17];
    float* out = (float*)d_out;
    char* W = (char*)d_ws;

    // byte layout (~95.5 MB peak)
    unsigned short* wqs_b = (unsigned short*)(W + 0);         // 1536x512
    unsigned short* wqc_b = (unsigned short*)(W + 1572864);   // 1536x768
    unsigned short* wo_b  = (unsigned short*)(W + 3932160);   // 512x512
    unsigned short* w1_b  = (unsigned short*)(W + 4456448);   // 2048x512
    unsigned short* w2_b  = (unsigned short*)(W + 6553600);   // 512x2048
    unsigned short* condb = (unsigned short*)(W + 8650752);   // 616x768
    float* mod            = (float*)(W + 9596928);            // 8x3072
    float* ct             = (float*)(W + 9695232);            // 1101x32 float2
    unsigned short* hmod  = (unsigned short*)(W + 9977088);   // 8192x512 bf16
    unsigned short* obuf  = hmod;                             // overlays hmod (dead post-qkv)
    unsigned short* qbuf  = (unsigned short*)(W + 18365696);  // 64x1024x64 bf16
    unsigned short* kbuf  = (unsigned short*)(W + 26754304);  // 64x1101x64 bf16
    unsigned short* vTb   = (unsigned short*)(W + 35772672);  // 64x64x1152 bf16
    unsigned short* h2    = vTb;                              // overlays vT (dead post-attn)
    unsigned short* mbuf  = (unsigned short*)(W + 45209856);  // 8192x2048 bf16
    float* x1             = (float*)(W + 78764288);           // 8x512x1024 f32
    float* sebuf          = (float*)(W + 45209920);           // 8x768 f32 (pre-MLP1 liveness)

    PrepArgs pa;
    pa.src[0] = qkvsw; pa.dst[0] = wqs_b; pa.n[0] = 1536 * 512;
    pa.src[1] = qkvcw; pa.dst[1] = wqc_b; pa.n[1] = 1536 * 768;
    pa.src[2] = outw;  pa.dst[2] = wo_b;  pa.n[2] = 512 * 512;
    pa.src[3] = w1;    pa.dst[3] = w1_b;  pa.n[3] = 2048 * 512;
    pa.src[4] = w2;    pa.dst[4] = w2_b;  pa.n[4] = 512 * 2048;
    pa.src[5] = cond;  pa.dst[5] = condb; pa.n[5] = 616 * 768;
    pa.freqs = ropef; pa.ct = ct;
    pa.emb = femb; pa.mbias = mod_b; pa.mod = mod; pa.se = sebuf;
    k_prep<<<dim3(1152, 8), 256, 0, stream>>>(pa);
    k_mod<<<dim3(12, 8, 8), 256, 0, stream>>>(sebuf, mod_w, mod);

    k_rms2d_mod_t<<<dim3(16, BATCH), 256, 0, stream>>>(x, n1s, mod, 0, 512, hmod);
    // qkv (spatial): fused RoPE/RMS/V^T epilogue
    k_gemm_qkv<0><<<dim3(12, 64), 256, 0, stream>>>(hmod, wqs_b, ct, qn, kn,
                                                    qbuf, kbuf, vTb);
    // qkv (cond): k/v tiles only (nOff=512)
    k_gemm_qkv<1><<<dim3(8, 5), 256, 0, stream>>>(condb, wqc_b, ct, qn, kn,
                                                  qbuf, kbuf, vTb);
    k_attn_v8<<<dim3(1024), 256, 0, stream>>>(qbuf, kbuf, vTb, obuf);
    // out-proj: x1 = x + g1*(obuf @ Wo^T + outb)  (channel-major f32), 128x64 2-phase
    k_gemm_mfma<1, 128, 64><<<dim3(8, 64), 256, 0, stream>>>(
        obuf, wo_b, x1, 8192, 512, 512, outb, mod + 2 * 512, x);
    k_rms2d_mod_t<<<dim3(16, BATCH), 256, 0, stream>>>(x1, n2s, mod, 3 * 512, 4 * 512, h2);
    // MLP1 + fast gelu -> bf16 [8192,2048], 128x128 2-phase (1024 blocks)
    k_gemm_mfma<2, 128, 128><<<dim3(16, 64), 256, 0, stream>>>(
        h2, w1_b, mbuf, 8192, 2048, 512, b1, nullptr, nullptr);
    // MLP2 + gate + residual -> d_out (channel-major f32), 128x64 2-phase
    k_gemm_mfma<1, 128, 64><<<dim3(8, 64), 256, 0, stream>>>(
        mbuf, w2_b, out, 8192, 512, 2048, b2, mod + 5 * 512, x1);
}

// Round 14
// 244.376 us; speedup vs baseline: 1.4181x; 1.0867x over previous
//
#include <hip/hip_runtime.h>

// FluxUNet fused block — round 14: qkv GEMM reshaped to 128x64 tile / 32x64 per wave
// (acc[2][4] = 32 VGPR, breaks the 132-VGPR occupancy cliff). Rest = r13.
// B=8, C=512, HW=1024, S=77, E=768, NH=8, HD=64, HID=2048, T=1101.
constexpr int BATCH = 8, CH = 512, HWN = 1024, SEQ = 77, EMB = 768;
constexpr int NHEAD = 8, HDIM = 64, HIDDEN = 2048, TTOT = 1101;
constexpr int VSTRIDE = 1152;  // padded t-stride for transposed V

typedef short bhalf8 __attribute__((ext_vector_type(8)));
typedef float f32x4 __attribute__((ext_vector_type(4)));

__device__ __forceinline__ unsigned short f2bf(float f) {
    unsigned u = __builtin_bit_cast(unsigned, f);
    unsigned r = (u + 0x7fffu + ((u >> 16) & 1u)) >> 16;
    return (unsigned short)r;
}
__device__ __forceinline__ unsigned cvtpk(float a, float b) {
    unsigned r;
    asm("v_cvt_pk_bf16_f32 %0, %1, %2" : "=v"(r) : "v"(a), "v"(b));
    return r;
}
// gelu_tanh via identity 0.5(1+tanh(u)) = 1 - 1/(e^{2u}+1); e^{2u} = 2^{2u*log2e}.
__device__ __forceinline__ float gelu_fast(float v) {
    float c = v * v * v;
    float z = fmaf(v, 2.3022082f, c * 0.10294324f);
    float e = exp2f(z) + 1.0f;
    float r;
    asm("v_rcp_f32 %0, %1" : "=v"(r) : "v"(e));
    return v - v * r;
}
// XOR-swizzle on a 128B-row-stride LDS tile (region base must be 1024B-aligned).
__device__ __forceinline__ int swz(int b) { return b ^ ((b >> 3) & 0x70); }

// async global->LDS 16B: LDS dest = wave-uniform base + lane*16.
__device__ __forceinline__ void gload16(const void* g, void* l) {
    __builtin_amdgcn_global_load_lds(
        (const __attribute__((address_space(1))) unsigned int*)g,
        (__attribute__((address_space(3))) unsigned int*)l, 16, 0, 0);
}

// ---------- merged prep: casts (y<6), rope table (y==6),
// ----------             y==7: mod bias-init / silu(emb) ----------
struct PrepArgs {
    const float* src[6];
    unsigned short* dst[6];
    int n[6];
    const float* freqs;
    float* ct;
    const float* emb;
    const float* mbias;
    float* mod;
    float* se;       // silu(emb) [8][768]
};
__global__ void k_prep(PrepArgs a) {
    int y = blockIdx.y;
    int bx = blockIdx.x;
    int tid = threadIdx.x;
    if (y < 6) {
        int i = (bx * 256 + tid) * 4;
        if (i >= a.n[y]) return;
        float4 v = *(const float4*)&a.src[y][i];
        ushort4 o = {f2bf(v.x), f2bf(v.y), f2bf(v.z), f2bf(v.w)};
        *(ushort4*)&a.dst[y][i] = o;
    } else if (y == 6) {
        int i = bx * 256 + tid;
        if (i >= TTOT * 32) return;
        int t = i >> 5, j = i & 31;
        float ang;
        if (t < HWN) {
            ang = (float)(t >> 5) * a.freqs[2 * j] + (float)(t & 31) * a.freqs[2 * j + 1];
        } else {
            float inv = expf(-(float)j * (9.210340371976184f / 32.0f));
            ang = (float)(t - HWN) * inv;
        }
        a.ct[i * 2] = cosf(ang);
        a.ct[i * 2 + 1] = sinf(ang);
    } else {
        if (bx < 24) {            // mod = bias (atomic partials land on top)
            int i = bx * 1024 + tid * 4;           // i = b*3072 + j, j%4==0
            int j = i - (i / (6 * CH)) * (6 * CH);
            *(float4*)&a.mod[i] = *(const float4*)&a.mbias[j];
        } else if (bx >= 32 && bx < 38) {  // silu(final_emb) -> se [6144 floats]
            int i = (bx - 32) * 1024 + tid * 4;
            float4 v = *(const float4*)&a.emb[i];
            float4 o;
            o.x = v.x / (1.0f + expf(-v.x));
            o.y = v.y / (1.0f + expf(-v.y));
            o.z = v.z / (1.0f + expf(-v.z));
            o.w = v.w / (1.0f + expf(-v.w));
            *(float4*)&a.se[i] = o;
        }
    }
}

// ---------- modulation partials: mod[b][j] += sum_{e in chunk} se[b][e] * w[e][j] ----------
__global__ __launch_bounds__(256) void k_mod(const float* __restrict__ se,
        const float* __restrict__ w, float* __restrict__ mod) {
    int jb = blockIdx.x, b = blockIdx.y, ec = blockIdx.z;
    int j = jb * 256 + threadIdx.x;
    const float* sb = se + b * EMB + ec * 96;
    const float* wb = w + (size_t)(ec * 96) * (6 * CH) + j;
    float acc = 0.f;
    #pragma unroll 8
    for (int e = 0; e < 96; ++e) acc = fmaf(sb[e], wb[(size_t)e * (6 * CH)], acc);
    atomicAdd(&mod[b * (6 * CH) + j], acc);
}

// ------- RMSNorm(channel) + adaLN modulate + transpose -> bf16 token-major -------
__global__ __launch_bounds__(256) void k_rms2d_mod_t(const float* __restrict__ xin,
        const float* __restrict__ sw, const float* __restrict__ mod, int shoff, int scoff,
        unsigned short* __restrict__ outp) {
    __shared__ float part[4][64];
    __shared__ float rinv[64];
    int b = blockIdx.y;
    int n0 = blockIdx.x * 64;
    int tid = threadIdx.x;
    const float* xb = xin + (size_t)b * CH * HWN;
    {
        int n = n0 + (tid & 63);
        int cg = tid >> 6;
        float ss = 0.f;
        #pragma unroll 8
        for (int c = cg * 128; c < cg * 128 + 128; ++c) {
            float v = xb[(size_t)c * HWN + n];
            ss = fmaf(v, v, ss);
        }
        part[cg][tid & 63] = ss;
    }
    __syncthreads();
    if (tid < 64) {
        float s = part[0][tid] + part[1][tid] + part[2][tid] + part[3][tid];
        rinv[tid] = rsqrtf(s * (1.0f / CH) + 1e-6f);
    }
    __syncthreads();
    int n = n0 + (tid >> 2);
    int cq = tid & 3;
    float r = rinv[tid >> 2];
    const float* mb = mod + b * (6 * CH);
    unsigned short* orow = outp + ((size_t)(b * HWN + n)) * CH;
    for (int jc = 0; jc < 16; ++jc) {
        int c = cq * 128 + jc * 8;
        bhalf8 o;
        #pragma unroll
        for (int u = 0; u < 8; ++u) {
            int cc = c + u;
            float v = xb[(size_t)cc * HWN + n];
            float y = v * r * sw[cc] * (1.0f + mb[scoff + cc]) + mb[shoff + cc];
            o[u] = (short)f2bf(y);
        }
        *(bhalf8*)&orow[c] = o;
    }
}

// ------- bf16 MFMA GEMM, 2-phase double-buffered (prefetch t+1 before compute t) -------
// A [M][K], Bt [N][K] bf16 row-major. K%64==0, N%BN==0, M row-clamped.
// EPI=1: f32 channel-major residual+gate (BM=128).  EPI=2: bf16 gelu token-major.
template <int EPI, int BM, int BN>
__global__ __launch_bounds__(256) void k_gemm_mfma(
        const unsigned short* __restrict__ A, const unsigned short* __restrict__ Bt,
        void* __restrict__ OutV, int M, int N, int K,
        const float* __restrict__ bias, const float* __restrict__ gate,
        const float* __restrict__ res) {
    constexpr int WM = BM / 2, WN = BN / 2;
    constexpr int MI = WM / 16, NI = WN / 16;
    constexpr int CA = BM / 8, CB = BN / 8, CW = (CA + CB) / 4;
    constexpr int BUF = (BM + BN) * 128;
    __shared__ __align__(1024) char SM[2 * BUF];
    int tid = threadIdx.x;
    int w = tid >> 6, l = tid & 63, lg = l >> 4, ll = l & 15;
    int wr = w >> 1, wc = w & 1;
    int m0 = blockIdx.y * BM, n0 = blockIdx.x * BN;
    int r8 = l >> 3, c16 = (l & 7) * 16;
    f32x4 acc[MI][NI] = {};
    const char* Ac = (const char*)A;
    const char* Bc = (const char*)Bt;
    size_t rowBytes = (size_t)K * 2;
    int nt = K >> 6;

    auto stage = [&](int t, int bsel) {
        char* As = SM + bsel * BUF;
        char* Bs = As + BM * 128;
        int k0 = t * 64;
        #pragma unroll
        for (int i = 0; i < CW; ++i) {
            int c = w * CW + i;
            if (c < CA) {
                int row = c * 8 + r8;
                int off = c16 ^ ((row & 7) << 4);
                int ar = m0 + row;
                if (ar > M - 1) ar = M - 1;
                gload16(Ac + (size_t)ar * rowBytes + k0 * 2 + off, As + c * 1024);
            } else {
                int cc = c - CA;
                int row = cc * 8 + r8;
                int off = c16 ^ ((row & 7) << 4);
                gload16(Bc + (size_t)(n0 + row) * rowBytes + k0 * 2 + off, Bs + cc * 1024);
            }
        }
    };
    stage(0, 0);
    __syncthreads();  // tile 0 landed
    int cur = 0;
    for (int t = 0; t < nt; ++t) {
        if (t + 1 < nt) stage(t + 1, cur ^ 1);  // latency hides under compute of tile t
        char* As = SM + cur * BUF;
        char* Bs = As + BM * 128;
        #pragma unroll
        for (int ks = 0; ks < 2; ++ks) {
            bhalf8 af[MI], bf[NI];
            #pragma unroll
            for (int mi = 0; mi < MI; ++mi)
                af[mi] = *(const bhalf8*)(As + swz((wr * WM + mi * 16 + ll) * 128 + ks * 64 + lg * 16));
            #pragma unroll
            for (int ni = 0; ni < NI; ++ni)
                bf[ni] = *(const bhalf8*)(Bs + swz((wc * WN + ni * 16 + ll) * 128 + ks * 64 + lg * 16));
            __builtin_amdgcn_s_setprio(1);
            #pragma unroll
            for (int mi = 0; mi < MI; ++mi)
                #pragma unroll
                for (int ni = 0; ni < NI; ++ni)
                    acc[mi][ni] = __builtin_amdgcn_mfma_f32_16x16x32_bf16(af[mi], bf[ni], acc[mi][ni], 0, 0, 0);
            __builtin_amdgcn_s_setprio(0);
        }
        __syncthreads();  // next tile landed; all waves done with cur buffers
        cur ^= 1;
    }
    if (EPI == 2) {
        unsigned short* Out = (unsigned short*)OutV;
        #pragma unroll
        for (int mi = 0; mi < MI; ++mi)
            #pragma unroll
            for (int ni = 0; ni < NI; ++ni) {
                int col = n0 + wc * WN + ni * 16 + ll;
                float bv = bias[col];
                #pragma unroll
                for (int r = 0; r < 4; ++r) {
                    int mrow = m0 + wr * WM + mi * 16 + 4 * lg + r;
                    Out[(size_t)mrow * N + col] = f2bf(gelu_fast(acc[mi][ni][r] + bv));
                }
            }
    } else {
        float* Out = (float*)OutV;
        int bidx = m0 >> 10;
        int hw0 = m0 & 1023;
        const float* resb = res + (size_t)bidx * N * HWN;
        float* outb_ = Out + (size_t)bidx * N * HWN;
        #pragma unroll
        for (int ni = 0; ni < NI; ++ni) {
            int ch = n0 + wc * WN + ni * 16 + ll;
            float g = gate[bidx * (6 * CH) + ch];
            float bv = bias[ch];
            #pragma unroll
            for (int mi = 0; mi < MI; ++mi) {
                int t = hw0 + wr * WM + mi * 16 + 4 * lg;
                float4 r4 = *(const float4*)&resb[(size_t)ch * HWN + t];
                f32x4 a = acc[mi][ni];
                float4 o;
                o.x = r4.x + g * (a[0] + bv);
                o.y = r4.y + g * (a[1] + bv);
                o.z = r4.z + g * (a[2] + bv);
                o.w = r4.w + g * (a[3] + bv);
                *(float4*)&outb_[(size_t)ch * HWN + t] = o;
            }
        }
    }
}

// ------- qkv GEMM, 128x64 tile (4 waves x 32x64, acc[2][4]=32 VGPR) -------
// Fused RoPE + qk-RMSNorm + head-split + V-transpose. Each n-block = one head slice.
// COND=0: A=hmod [8192][512], grid (24,64), nOff=0.
// COND=1: A=condb [616][768], grid (16,5), nOff=512 (k/v only).
template <int COND>
__global__ __launch_bounds__(256) void k_gemm_qkv(
        const unsigned short* __restrict__ A, const unsigned short* __restrict__ Bt,
        const float* __restrict__ ct, const float* __restrict__ qn,
        const float* __restrict__ kn, unsigned short* __restrict__ qb,
        unsigned short* __restrict__ kb, unsigned short* __restrict__ vT) {
    constexpr int M = COND ? 616 : 8192;
    constexpr int K = COND ? 768 : 512;
    constexpr int nOff = COND ? 512 : 0;
    __shared__ __align__(1024) char SMEM[24576];  // loop: A 16K + B 8K; epi: stg[128][72]
    int tid = threadIdx.x;
    int w = tid >> 6, l = tid & 63, lg = l >> 4, ll = l & 15;
    int m0 = blockIdx.y * 128, n0 = nOff + blockIdx.x * 64;
    int r8 = l >> 3, c16 = (l & 7) * 16;
    f32x4 acc[2][4] = {};
    const char* Ac = (const char*)A;
    const char* Bc = (const char*)Bt;
    constexpr size_t rowBytes = (size_t)K * 2;
    for (int k0 = 0; k0 < K; k0 += 64) {
        __syncthreads();
        #pragma unroll
        for (int i = 0; i < 6; ++i) {
            int c = w * 6 + i;
            if (c < 16) {          // A chunks: rows 0..127
                int row = c * 8 + r8;
                int off = c16 ^ ((row & 7) << 4);
                int ar = m0 + row;
                if (ar > M - 1) ar = M - 1;
                gload16(Ac + (size_t)ar * rowBytes + k0 * 2 + off, SMEM + c * 1024);
            } else {               // B chunks: rows 0..63
                int cc = c - 16;
                int row = cc * 8 + r8;
                int off = c16 ^ ((row & 7) << 4);
                gload16(Bc + (size_t)(n0 + row) * rowBytes + k0 * 2 + off,
                        SMEM + 16384 + cc * 1024);
            }
        }
        __syncthreads();
        #pragma unroll
        for (int ks = 0; ks < 2; ++ks) {
            bhalf8 af[2], bf[4];
            #pragma unroll
            for (int mi = 0; mi < 2; ++mi)
                af[mi] = *(const bhalf8*)(SMEM + swz((w * 32 + mi * 16 + ll) * 128 + ks * 64 + lg * 16));
            #pragma unroll
            for (int ni = 0; ni < 4; ++ni)
                bf[ni] = *(const bhalf8*)(SMEM + 16384 + swz((ni * 16 + ll) * 128 + ks * 64 + lg * 16));
            __builtin_amdgcn_s_setprio(1);
            #pragma unroll
            for (int mi = 0; mi < 2; ++mi)
                #pragma unroll
                for (int ni = 0; ni < 4; ++ni)
                    acc[mi][ni] = __builtin_amdgcn_mfma_f32_16x16x32_bf16(af[mi], bf[ni], acc[mi][ni], 0, 0, 0);
            __builtin_amdgcn_s_setprio(0);
        }
    }
    int type = n0 >> 9;  // 0 q, 1 k, >=2 v
    const float2* ct2 = (const float2*)ct;

    if (type >= 2) {  // ---- V: direct transposed bf16 writes (head = (n0-1024)>>6) ----
        int hd = (n0 - 1024) >> 6;
        #pragma unroll
        for (int ni = 0; ni < 4; ++ni) {
            int d = ni * 16 + ll;
            #pragma unroll
            for (int mi = 0; mi < 2; ++mi) {
                int rowL = m0 + w * 32 + mi * 16 + 4 * lg;
                if (COND == 0) {
                    int b = rowL >> 10, t = rowL & 1023;
                    uint2 pk = {cvtpk(acc[mi][ni][0], acc[mi][ni][1]),
                                cvtpk(acc[mi][ni][2], acc[mi][ni][3])};
                    *(uint2*)&vT[((size_t)(b * 8 + hd) * 64 + d) * VSTRIDE + t] = pk;
                } else {
                    #pragma unroll
                    for (int r = 0; r < 4; ++r) {
                        int row = rowL + r;
                        if (row < M) {
                            int b = row / 77, s = row - b * 77;
                            vT[((size_t)(b * 8 + hd) * 64 + d) * VSTRIDE + 1024 + s] =
                                f2bf(acc[mi][ni][r]);
                        }
                    }
                }
            }
        }
        return;
    }
    // ---- Q/K: RoPE + RMSNorm + scale, then LDS-transpose for coalesced stores ----
    const float* wnt = (type == 0) ? qn : kn;
    float wscale = (type == 0) ? 0.18033688011112042f : 1.0f;  // 0.125*log2e folded
    float sgn = (ll & 1) ? 1.f : -1.f;
    #pragma unroll
    for (int mi = 0; mi < 2; ++mi) {
        int rowL = m0 + w * 32 + mi * 16 + 4 * lg;
        int tt[4];
        #pragma unroll
        for (int r = 0; r < 4; ++r) {
            if (COND == 0) tt[r] = (rowL + r) & 1023;
            else {
                int row = rowL + r;
                if (row > M - 1) row = M - 1;
                int b = row / 77;
                tt[r] = 1024 + (row - b * 77);
            }
        }
        #pragma unroll
        for (int ni = 0; ni < 4; ++ni) {
            int jjv = (ni * 16 + ll) >> 1;
            f32x4 a = acc[mi][ni], p;
            #pragma unroll
            for (int r = 0; r < 4; ++r) p[r] = __shfl_xor(a[r], 1);
            #pragma unroll
            for (int r = 0; r < 4; ++r) {
                float2 cs = ct2[tt[r] * 32 + jjv];
                a[r] = fmaf(sgn * p[r], cs.y, a[r] * cs.x);
            }
            acc[mi][ni] = a;
        }
        f32x4 ss = {};
        #pragma unroll
        for (int ni = 0; ni < 4; ++ni)
            #pragma unroll
            for (int r = 0; r < 4; ++r) ss[r] = fmaf(acc[mi][ni][r], acc[mi][ni][r], ss[r]);
        #pragma unroll
        for (int msk = 1; msk < 16; msk <<= 1)
            #pragma unroll
            for (int r = 0; r < 4; ++r) ss[r] += __shfl_xor(ss[r], msk);
        #pragma unroll
        for (int r = 0; r < 4; ++r)
            ss[r] = rsqrtf(ss[r] * (1.0f / 64.f) + 1.1920929e-07f) * wscale;
        #pragma unroll
        for (int ni = 0; ni < 4; ++ni) {
            float wv = wnt[ni * 16 + ll];
            #pragma unroll
            for (int r = 0; r < 4; ++r) acc[mi][ni][r] *= ss[r] * wv;
        }
    }
    __syncthreads();
    unsigned short* stg = (unsigned short*)SMEM;  // [128][72]
    #pragma unroll
    for (int mi = 0; mi < 2; ++mi)
        #pragma unroll
        for (int ni = 0; ni < 4; ++ni) {
            int colL = ni * 16 + ll;
            int rowL = w * 32 + mi * 16 + 4 * lg;
            #pragma unroll
            for (int r = 0; r < 4; ++r)
                stg[(rowL + r) * 72 + colL] = f2bf(acc[mi][ni][r]);
        }
    __syncthreads();
    int rowO = tid >> 1, half = tid & 1;
    int rowG = m0 + rowO;
    if (COND == 1 && rowG >= M) return;
    int b, t;
    if (COND == 0) { b = rowG >> 10; t = rowG & 1023; }
    else { b = rowG / 77; t = 1024 + (rowG - b * 77); }
    unsigned short* dst;
    if (type == 0) dst = qb + ((size_t)(b * 8 + (n0 >> 6)) * HWN + t) * 64 + half * 32;
    else dst = kb + ((size_t)(b * 8 + ((n0 - 512) >> 6)) * TTOT + t) * 64 + half * 32;
    #pragma unroll
    for (int i = 0; i < 4; ++i)
        *(bhalf8*)&dst[i * 8] = *(const bhalf8*)&stg[rowO * 72 + half * 32 + i * 8];
}

// -------- attn v8: no-shift exp2 softmax, MFMA-accumulated L, double-buffered K/V --------
// LDS 40KB: buf0 K[0,8K) V[8K,16K); buf1 K[16K,24K) V[24K,32K); P [32K,40K).
__global__ __launch_bounds__(256) void k_attn_v8(const unsigned short* __restrict__ qb,
        const unsigned short* __restrict__ kbuf, const unsigned short* __restrict__ vT,
        unsigned short* __restrict__ ob) {
    __shared__ __align__(1024) char smc[40960];
    int f = blockIdx.x;
    int xcd = f & 7, n = f >> 3;
    int q0 = (n & 15) * 64;
    int bh = ((n >> 4) << 3) | xcd;
    int tid = threadIdx.x;
    int w = tid >> 6, l = tid & 63, lg = l >> 4, ll = l & 15;
    int r8 = l >> 3, c16 = (l & 7) * 16;
    bhalf8 qf[2];
    {
        const unsigned short* qbase = qb + ((size_t)bh * HWN + q0 + w * 16) * 64;
        #pragma unroll
        for (int ks = 0; ks < 2; ++ks)
            qf[ks] = *(const bhalf8*)&qbase[ll * 64 + ks * 32 + lg * 8];
    }
    bhalf8 onesf;
    #pragma unroll
    for (int i = 0; i < 8; ++i) onesf[i] = (short)0x3F80;  // bf16 1.0
    f32x4 accO[4] = {};   // O^T[d=d4*16+4lg+r][q=ll]
    f32x4 Lacc = {};      // all 4 rows = sum_k P[k][q=ll]
    const char* kgl = (const char*)kbuf + (size_t)bh * TTOT * 128;
    const char* vgl = (const char*)vT + (size_t)bh * 64 * (VSTRIDE * 2);
    char* pw = smc + 32768 + w * 2048 + ll * 128;
    int pswz = (ll & 7) << 4;

    auto stage = [&](int kt, int bsel) {
        char* base = smc + bsel * 16384;
        #pragma unroll
        for (int i = 0; i < 4; ++i) {
            int c = w * 4 + i;
            if (c < 8) {  // K chunk: rows = keys
                int row = c * 8 + r8;
                int t = kt * 64 + row;
                if (t > TTOT - 1) t = TTOT - 1;  // clamped rows are softmax-masked
                gload16(kgl + (size_t)t * 128 + (c16 ^ ((row & 7) << 4)), base + c * 1024);
            } else {      // V^T chunk: rows = d
                int row = (c - 8) * 8 + r8;
                gload16(vgl + (size_t)row * (VSTRIDE * 2) + kt * 128 + (c16 ^ ((row & 7) << 4)),
                        base + 8192 + (c - 8) * 1024);
            }
        }
    };
    stage(0, 0);
    __syncthreads();  // tile 0 landed
    for (int kt = 0; kt < 18; ++kt) {
        int cur = kt & 1;
        if (kt < 17) stage(kt + 1, cur ^ 1);  // issue next tile; latency hides under compute
        char* kl = smc + cur * 16384;
        char* vl = kl + 8192;
        // S^T = K x Q
        f32x4 s[4] = {};
        __builtin_amdgcn_s_setprio(1);
        #pragma unroll
        for (int ks = 0; ks < 2; ++ks) {
            bhalf8 kf[4];
            #pragma unroll
            for (int k4 = 0; k4 < 4; ++k4)
                kf[k4] = *(const bhalf8*)(kl + swz((k4 * 16 + ll) * 128 + ks * 64 + lg * 16));
            #pragma unroll
            for (int k4 = 0; k4 < 4; ++k4)
                s[k4] = __builtin_amdgcn_mfma_f32_16x16x32_bf16(kf[k4], qf[ks], s[k4], 0, 0, 0);
        }
        __builtin_amdgcn_s_setprio(0);
        if (kt == 17) {  // mask tail keys (key index lane-local: k4*16 + 4lg + r)
            int kb0 = kt * 64 + 4 * lg;
            #pragma unroll
            for (int k4 = 0; k4 < 4; ++k4)
                #pragma unroll
                for (int r = 0; r < 4; ++r)
                    if (kb0 + k4 * 16 + r >= TTOT) s[k4][r] = -1e30f;
        }
        // softmax, no shift: P = exp2(s); uniform scale cancels in O=PV/L.
        #pragma unroll
        for (int k4 = 0; k4 < 4; ++k4) {
            float p0 = exp2f(s[k4][0]), p1 = exp2f(s[k4][1]);
            float p2 = exp2f(s[k4][2]), p3 = exp2f(s[k4][3]);
            uint2 pk = {cvtpk(p0, p1), cvtpk(p2, p3)};
            *(uint2*)(pw + ((k4 * 32 + lg * 8) ^ pswz)) = pk;
        }
        // O^T += V^T x P ; L += ones x P
        __builtin_amdgcn_s_setprio(1);
        #pragma unroll
        for (int ks = 0; ks < 2; ++ks) {
            bhalf8 vf[4];
            #pragma unroll
            for (int d4 = 0; d4 < 4; ++d4)
                vf[d4] = *(const bhalf8*)(vl + swz((d4 * 16 + ll) * 128 + ks * 64 + lg * 16));
            bhalf8 pf = *(const bhalf8*)(smc + 32768 + w * 2048 + swz(ll * 128 + ks * 64 + lg * 16));
            Lacc = __builtin_amdgcn_mfma_f32_16x16x32_bf16(onesf, pf, Lacc, 0, 0, 0);
            #pragma unroll
            for (int d4 = 0; d4 < 4; ++d4)
                accO[d4] = __builtin_amdgcn_mfma_f32_16x16x32_bf16(vf[d4], pf, accO[d4], 0, 0, 0);
        }
        __builtin_amdgcn_s_setprio(0);
        __syncthreads();  // next-tile loads landed; all waves done with cur buffers
    }
    // epilogue: /L, transpose O^T -> [q][d] via LDS, coalesced stores
    {
        float inv = 1.0f / Lacc[0];
        int orow = w * 16 + ll;
        char* po = smc + orow * 128;
        int oswz = (orow & 7) << 4;
        #pragma unroll
        for (int d4 = 0; d4 < 4; ++d4) {
            uint2 pk = {cvtpk(accO[d4][0] * inv, accO[d4][1] * inv),
                        cvtpk(accO[d4][2] * inv, accO[d4][3] * inv)};
            *(uint2*)(po + ((d4 * 32 + lg * 8) ^ oswz)) = pk;
        }
    }
    __syncthreads();
    int b = bh >> 3, h = bh & 7;
    int row = tid >> 2, seg = tid & 3;
    bhalf8 v0 = *(const bhalf8*)(smc + swz(row * 128 + seg * 32));
    bhalf8 v1 = *(const bhalf8*)(smc + swz(row * 128 + seg * 32 + 16));
    unsigned short* dst = ob + ((size_t)(b * HWN + q0 + row)) * CH + h * 64 + seg * 16;
    *(bhalf8*)&dst[0] = v0;
    *(bhalf8*)&dst[8] = v1;
}

extern "C" void kernel_launch(void* const* d_in, const int* in_sizes, int n_in,
                              void* d_out, int out_size, void* d_ws, size_t ws_size,
                              hipStream_t stream) {
    const float* x     = (const float*)d_in[0];
    const float* cond  = (const float*)d_in[1];
    const float* femb  = (const float*)d_in[2];
    const float* mod_w = (const float*)d_in[3];
    const float* mod_b = (const float*)d_in[4];
    const float* n1s   = (const float*)d_in[5];
    const float* n2s   = (const float*)d_in[6];
    const float* qkvsw = (const float*)d_in[7];
    const float* qkvcw = (const float*)d_in[8];
    const float* ropef = (const float*)d_in[9];
    const float* qn    = (const float*)d_in[10];
    const float* kn    = (const float*)d_in[11];
    const float* outw  = (const float*)d_in[12];
    const float* outb  = (const float*)d_in[13];
    const float* w1    = (const float*)d_in[14];
    const float* b1    = (const float*)d_in[15];
    const float* w2    = (const float*)d_in[16];
    const float* b2    = (const float*)d_in[17];
    float* out = (float*)d_out;
    char* W = (char*)d_ws;

    // byte layout (~95.5 MB peak)
    unsigned short* wqs_b = (unsigned short*)(W + 0);         // 1536x512
    unsigned short* wqc_b = (unsigned short*)(W + 1572864);   // 1536x768
    unsigned short* wo_b  = (unsigned short*)(W + 3932160);   // 512x512
    unsigned short* w1_b  = (unsigned short*)(W + 4456448);   // 2048x512
    unsigned short* w2_b  = (unsigned short*)(W + 6553600);   // 512x2048
    unsigned short* condb = (unsigned short*)(W + 8650752);   // 616x768
    float* mod            = (float*)(W + 9596928);            // 8x3072
    float* ct             = (float*)(W + 9695232);            // 1101x32 float2
    unsigned short* hmod  = (unsigned short*)(W + 9977088);   // 8192x512 bf16
    unsigned short* obuf  = hmod;                             // overlays hmod (dead post-qkv)
    unsigned short* qbuf  = (unsigned short*)(W + 18365696);  // 64x1024x64 bf16
    unsigned short* kbuf  = (unsigned short*)(W + 26754304);  // 64x1101x64 bf16
    unsigned short* vTb   = (unsigned short*)(W + 35772672);  // 64x64x1152 bf16
    unsigned short* h2    = vTb;                              // overlays vT (dead post-attn)
    unsigned short* mbuf  = (unsigned short*)(W + 45209856);  // 8192x2048 bf16
    float* x1             = (float*)(W + 78764288);           // 8x512x1024 f32
    float* sebuf          = (float*)(W + 45209920);           // 8x768 f32 (pre-MLP1 liveness)

    PrepArgs pa;
    pa.src[0] = qkvsw; pa.dst[0] = wqs_b; pa.n[0] = 1536 * 512;
    pa.src[1] = qkvcw; pa.dst[1] = wqc_b; pa.n[1] = 1536 * 768;
    pa.src[2] = outw;  pa.dst[2] = wo_b;  pa.n[2] = 512 * 512;
    pa.src[3] = w1;    pa.dst[3] = w1_b;  pa.n[3] = 2048 * 512;
    pa.src[4] = w2;    pa.dst[4] = w2_b;  pa.n[4] = 512 * 2048;
    pa.src[5] = cond;  pa.dst[5] = condb; pa.n[5] = 616 * 768;
    pa.freqs = ropef; pa.ct = ct;
    pa.emb = femb; pa.mbias = mod_b; pa.mod = mod; pa.se = sebuf;
    k_prep<<<dim3(1152, 8), 256, 0, stream>>>(pa);
    k_mod<<<dim3(12, 8, 8), 256, 0, stream>>>(sebuf, mod_w, mod);

    k_rms2d_mod_t<<<dim3(16, BATCH), 256, 0, stream>>>(x, n1s, mod, 0, 512, hmod);
    // qkv (spatial): fused RoPE/RMS/V^T epilogue, 128x64 tiles
    k_gemm_qkv<0><<<dim3(24, 64), 256, 0, stream>>>(hmod, wqs_b, ct, qn, kn,
                                                    qbuf, kbuf, vTb);
    // qkv (cond): k/v tiles only (nOff=512), 128x64 tiles
    k_gemm_qkv<1><<<dim3(16, 5), 256, 0, stream>>>(condb, wqc_b, ct, qn, kn,
                                                   qbuf, kbuf, vTb);
    k_attn_v8<<<dim3(1024), 256, 0, stream>>>(qbuf, kbuf, vTb, obuf);
    // out-proj: x1 = x + g1*(obuf @ Wo^T + outb)  (channel-major f32), 128x64 2-phase
    k_gemm_mfma<1, 128, 64><<<dim3(8, 64), 256, 0, stream>>>(
        obuf, wo_b, x1, 8192, 512, 512, outb, mod + 2 * 512, x);
    k_rms2d_mod_t<<<dim3(16, BATCH), 256, 0, stream>>>(x1, n2s, mod, 3 * 512, 4 * 512, h2);
    // MLP1 + fast gelu -> bf16 [8192,2048], 128x128 2-phase (1024 blocks)
    k_gemm_mfma<2, 128, 128><<<dim3(16, 64), 256, 0, stream>>>(
        h2, w1_b, mbuf, 8192, 2048, 512, b1, nullptr, nullptr);
    // MLP2 + gate + residual -> d_out (channel-major f32), 128x64 2-phase
    k_gemm_mfma<1, 128, 64><<<dim3(8, 64), 256, 0, stream>>>(
        mbuf, w2_b, out, 8192, 512, 2048, b2, mod + 5 * 512, x1);
}

// Round 15
// 220.177 us; speedup vs baseline: 1.5740x; 1.1099x over previous
//
#include <hip/hip_runtime.h>

// FluxUNet fused block — round 15: grid-order swap (blockIdx.x = m-tile) so blocks
// sharing an A-panel land on one XCD (L2 reuse; r14 showed 140MB FETCH = 4-5x A
// over-fetch on MLP2). Rest identical to r14.
// B=8, C=512, HW=1024, S=77, E=768, NH=8, HD=64, HID=2048, T=1101.
constexpr int BATCH = 8, CH = 512, HWN = 1024, SEQ = 77, EMB = 768;
constexpr int NHEAD = 8, HDIM = 64, HIDDEN = 2048, TTOT = 1101;
constexpr int VSTRIDE = 1152;  // padded t-stride for transposed V

typedef short bhalf8 __attribute__((ext_vector_type(8)));
typedef float f32x4 __attribute__((ext_vector_type(4)));

__device__ __forceinline__ unsigned short f2bf(float f) {
    unsigned u = __builtin_bit_cast(unsigned, f);
    unsigned r = (u + 0x7fffu + ((u >> 16) & 1u)) >> 16;
    return (unsigned short)r;
}
__device__ __forceinline__ unsigned cvtpk(float a, float b) {
    unsigned r;
    asm("v_cvt_pk_bf16_f32 %0, %1, %2" : "=v"(r) : "v"(a), "v"(b));
    return r;
}
// gelu_tanh via identity 0.5(1+tanh(u)) = 1 - 1/(e^{2u}+1); e^{2u} = 2^{2u*log2e}.
__device__ __forceinline__ float gelu_fast(float v) {
    float c = v * v * v;
    float z = fmaf(v, 2.3022082f, c * 0.10294324f);
    float e = exp2f(z) + 1.0f;
    float r;
    asm("v_rcp_f32 %0, %1" : "=v"(r) : "v"(e));
    return v - v * r;
}
// XOR-swizzle on a 128B-row-stride LDS tile (region base must be 1024B-aligned).
__device__ __forceinline__ int swz(int b) { return b ^ ((b >> 3) & 0x70); }

// async global->LDS 16B: LDS dest = wave-uniform base + lane*16.
__device__ __forceinline__ void gload16(const void* g, void* l) {
    __builtin_amdgcn_global_load_lds(
        (const __attribute__((address_space(1))) unsigned int*)g,
        (__attribute__((address_space(3))) unsigned int*)l, 16, 0, 0);
}

// ---------- merged prep: casts (y<6), rope table (y==6),
// ----------             y==7: mod bias-init / silu(emb) ----------
struct PrepArgs {
    const float* src[6];
    unsigned short* dst[6];
    int n[6];
    const float* freqs;
    float* ct;
    const float* emb;
    const float* mbias;
    float* mod;
    float* se;       // silu(emb) [8][768]
};
__global__ void k_prep(PrepArgs a) {
    int y = blockIdx.y;
    int bx = blockIdx.x;
    int tid = threadIdx.x;
    if (y < 6) {
        int i = (bx * 256 + tid) * 4;
        if (i >= a.n[y]) return;
        float4 v = *(const float4*)&a.src[y][i];
        ushort4 o = {f2bf(v.x), f2bf(v.y), f2bf(v.z), f2bf(v.w)};
        *(ushort4*)&a.dst[y][i] = o;
    } else if (y == 6) {
        int i = bx * 256 + tid;
        if (i >= TTOT * 32) return;
        int t = i >> 5, j = i & 31;
        float ang;
        if (t < HWN) {
            ang = (float)(t >> 5) * a.freqs[2 * j] + (float)(t & 31) * a.freqs[2 * j + 1];
        } else {
            float inv = expf(-(float)j * (9.210340371976184f / 32.0f));
            ang = (float)(t - HWN) * inv;
        }
        a.ct[i * 2] = cosf(ang);
        a.ct[i * 2 + 1] = sinf(ang);
    } else {
        if (bx < 24) {            // mod = bias (atomic partials land on top)
            int i = bx * 1024 + tid * 4;           // i = b*3072 + j, j%4==0
            int j = i - (i / (6 * CH)) * (6 * CH);
            *(float4*)&a.mod[i] = *(const float4*)&a.mbias[j];
        } else if (bx >= 32 && bx < 38) {  // silu(final_emb) -> se [6144 floats]
            int i = (bx - 32) * 1024 + tid * 4;
            float4 v = *(const float4*)&a.emb[i];
            float4 o;
            o.x = v.x / (1.0f + expf(-v.x));
            o.y = v.y / (1.0f + expf(-v.y));
            o.z = v.z / (1.0f + expf(-v.z));
            o.w = v.w / (1.0f + expf(-v.w));
            *(float4*)&a.se[i] = o;
        }
    }
}

// ---------- modulation partials: mod[b][j] += sum_{e in chunk} se[b][e] * w[e][j] ----------
__global__ __launch_bounds__(256) void k_mod(const float* __restrict__ se,
        const float* __restrict__ w, float* __restrict__ mod) {
    int jb = blockIdx.x, b = blockIdx.y, ec = blockIdx.z;
    int j = jb * 256 + threadIdx.x;
    const float* sb = se + b * EMB + ec * 96;
    const float* wb = w + (size_t)(ec * 96) * (6 * CH) + j;
    float acc = 0.f;
    #pragma unroll 8
    for (int e = 0; e < 96; ++e) acc = fmaf(sb[e], wb[(size_t)e * (6 * CH)], acc);
    atomicAdd(&mod[b * (6 * CH) + j], acc);
}

// ------- RMSNorm(channel) + adaLN modulate + transpose -> bf16 token-major -------
__global__ __launch_bounds__(256) void k_rms2d_mod_t(const float* __restrict__ xin,
        const float* __restrict__ sw, const float* __restrict__ mod, int shoff, int scoff,
        unsigned short* __restrict__ outp) {
    __shared__ float part[4][64];
    __shared__ float rinv[64];
    int b = blockIdx.y;
    int n0 = blockIdx.x * 64;
    int tid = threadIdx.x;
    const float* xb = xin + (size_t)b * CH * HWN;
    {
        int n = n0 + (tid & 63);
        int cg = tid >> 6;
        float ss = 0.f;
        #pragma unroll 8
        for (int c = cg * 128; c < cg * 128 + 128; ++c) {
            float v = xb[(size_t)c * HWN + n];
            ss = fmaf(v, v, ss);
        }
        part[cg][tid & 63] = ss;
    }
    __syncthreads();
    if (tid < 64) {
        float s = part[0][tid] + part[1][tid] + part[2][tid] + part[3][tid];
        rinv[tid] = rsqrtf(s * (1.0f / CH) + 1e-6f);
    }
    __syncthreads();
    int n = n0 + (tid >> 2);
    int cq = tid & 3;
    float r = rinv[tid >> 2];
    const float* mb = mod + b * (6 * CH);
    unsigned short* orow = outp + ((size_t)(b * HWN + n)) * CH;
    for (int jc = 0; jc < 16; ++jc) {
        int c = cq * 128 + jc * 8;
        bhalf8 o;
        #pragma unroll
        for (int u = 0; u < 8; ++u) {
            int cc = c + u;
            float v = xb[(size_t)cc * HWN + n];
            float y = v * r * sw[cc] * (1.0f + mb[scoff + cc]) + mb[shoff + cc];
            o[u] = (short)f2bf(y);
        }
        *(bhalf8*)&orow[c] = o;
    }
}

// ------- bf16 MFMA GEMM, 2-phase double-buffered; grid = (Mblocks, Nblocks) -------
// blockIdx.x = m-tile (XCD locality: same-A blocks share an XCD's L2).
// A [M][K], Bt [N][K] bf16 row-major. K%64==0, N%BN==0, M row-clamped.
// EPI=1: f32 channel-major residual+gate (BM=128).  EPI=2: bf16 gelu token-major.
template <int EPI, int BM, int BN>
__global__ __launch_bounds__(256) void k_gemm_mfma(
        const unsigned short* __restrict__ A, const unsigned short* __restrict__ Bt,
        void* __restrict__ OutV, int M, int N, int K,
        const float* __restrict__ bias, const float* __restrict__ gate,
        const float* __restrict__ res) {
    constexpr int WM = BM / 2, WN = BN / 2;
    constexpr int MI = WM / 16, NI = WN / 16;
    constexpr int CA = BM / 8, CB = BN / 8, CW = (CA + CB) / 4;
    constexpr int BUF = (BM + BN) * 128;
    __shared__ __align__(1024) char SM[2 * BUF];
    int tid = threadIdx.x;
    int w = tid >> 6, l = tid & 63, lg = l >> 4, ll = l & 15;
    int wr = w >> 1, wc = w & 1;
    int m0 = blockIdx.x * BM, n0 = blockIdx.y * BN;
    int r8 = l >> 3, c16 = (l & 7) * 16;
    f32x4 acc[MI][NI] = {};
    const char* Ac = (const char*)A;
    const char* Bc = (const char*)Bt;
    size_t rowBytes = (size_t)K * 2;
    int nt = K >> 6;

    auto stage = [&](int t, int bsel) {
        char* As = SM + bsel * BUF;
        char* Bs = As + BM * 128;
        int k0 = t * 64;
        #pragma unroll
        for (int i = 0; i < CW; ++i) {
            int c = w * CW + i;
            if (c < CA) {
                int row = c * 8 + r8;
                int off = c16 ^ ((row & 7) << 4);
                int ar = m0 + row;
                if (ar > M - 1) ar = M - 1;
                gload16(Ac + (size_t)ar * rowBytes + k0 * 2 + off, As + c * 1024);
            } else {
                int cc = c - CA;
                int row = cc * 8 + r8;
                int off = c16 ^ ((row & 7) << 4);
                gload16(Bc + (size_t)(n0 + row) * rowBytes + k0 * 2 + off, Bs + cc * 1024);
            }
        }
    };
    stage(0, 0);
    __syncthreads();  // tile 0 landed
    int cur = 0;
    for (int t = 0; t < nt; ++t) {
        if (t + 1 < nt) stage(t + 1, cur ^ 1);  // latency hides under compute of tile t
        char* As = SM + cur * BUF;
        char* Bs = As + BM * 128;
        #pragma unroll
        for (int ks = 0; ks < 2; ++ks) {
            bhalf8 af[MI], bf[NI];
            #pragma unroll
            for (int mi = 0; mi < MI; ++mi)
                af[mi] = *(const bhalf8*)(As + swz((wr * WM + mi * 16 + ll) * 128 + ks * 64 + lg * 16));
            #pragma unroll
            for (int ni = 0; ni < NI; ++ni)
                bf[ni] = *(const bhalf8*)(Bs + swz((wc * WN + ni * 16 + ll) * 128 + ks * 64 + lg * 16));
            __builtin_amdgcn_s_setprio(1);
            #pragma unroll
            for (int mi = 0; mi < MI; ++mi)
                #pragma unroll
                for (int ni = 0; ni < NI; ++ni)
                    acc[mi][ni] = __builtin_amdgcn_mfma_f32_16x16x32_bf16(af[mi], bf[ni], acc[mi][ni], 0, 0, 0);
            __builtin_amdgcn_s_setprio(0);
        }
        __syncthreads();  // next tile landed; all waves done with cur buffers
        cur ^= 1;
    }
    if (EPI == 2) {
        unsigned short* Out = (unsigned short*)OutV;
        #pragma unroll
        for (int mi = 0; mi < MI; ++mi)
            #pragma unroll
            for (int ni = 0; ni < NI; ++ni) {
                int col = n0 + wc * WN + ni * 16 + ll;
                float bv = bias[col];
                #pragma unroll
                for (int r = 0; r < 4; ++r) {
                    int mrow = m0 + wr * WM + mi * 16 + 4 * lg + r;
                    Out[(size_t)mrow * N + col] = f2bf(gelu_fast(acc[mi][ni][r] + bv));
                }
            }
    } else {
        float* Out = (float*)OutV;
        int bidx = m0 >> 10;
        int hw0 = m0 & 1023;
        const float* resb = res + (size_t)bidx * N * HWN;
        float* outb_ = Out + (size_t)bidx * N * HWN;
        #pragma unroll
        for (int ni = 0; ni < NI; ++ni) {
            int ch = n0 + wc * WN + ni * 16 + ll;
            float g = gate[bidx * (6 * CH) + ch];
            float bv = bias[ch];
            #pragma unroll
            for (int mi = 0; mi < MI; ++mi) {
                int t = hw0 + wr * WM + mi * 16 + 4 * lg;
                float4 r4 = *(const float4*)&resb[(size_t)ch * HWN + t];
                f32x4 a = acc[mi][ni];
                float4 o;
                o.x = r4.x + g * (a[0] + bv);
                o.y = r4.y + g * (a[1] + bv);
                o.z = r4.z + g * (a[2] + bv);
                o.w = r4.w + g * (a[3] + bv);
                *(float4*)&outb_[(size_t)ch * HWN + t] = o;
            }
        }
    }
}

// ------- qkv GEMM, 128x64 tile (4 waves x 32x64); grid = (Mblocks, Nblocks) -------
// Fused RoPE + qk-RMSNorm + head-split + V-transpose. Each n-block = one head slice.
// COND=0: A=hmod [8192][512], grid (64,24), nOff=0.
// COND=1: A=condb [616][768], grid (5,16), nOff=512 (k/v only).
template <int COND>
__global__ __launch_bounds__(256) void k_gemm_qkv(
        const unsigned short* __restrict__ A, const unsigned short* __restrict__ Bt,
        const float* __restrict__ ct, const float* __restrict__ qn,
        const float* __restrict__ kn, unsigned short* __restrict__ qb,
        unsigned short* __restrict__ kb, unsigned short* __restrict__ vT) {
    constexpr int M = COND ? 616 : 8192;
    constexpr int K = COND ? 768 : 512;
    constexpr int nOff = COND ? 512 : 0;
    __shared__ __align__(1024) char SMEM[24576];  // loop: A 16K + B 8K; epi: stg[128][72]
    int tid = threadIdx.x;
    int w = tid >> 6, l = tid & 63, lg = l >> 4, ll = l & 15;
    int m0 = blockIdx.x * 128, n0 = nOff + blockIdx.y * 64;
    int r8 = l >> 3, c16 = (l & 7) * 16;
    f32x4 acc[2][4] = {};
    const char* Ac = (const char*)A;
    const char* Bc = (const char*)Bt;
    constexpr size_t rowBytes = (size_t)K * 2;
    for (int k0 = 0; k0 < K; k0 += 64) {
        __syncthreads();
        #pragma unroll
        for (int i = 0; i < 6; ++i) {
            int c = w * 6 + i;
            if (c < 16) {          // A chunks: rows 0..127
                int row = c * 8 + r8;
                int off = c16 ^ ((row & 7) << 4);
                int ar = m0 + row;
                if (ar > M - 1) ar = M - 1;
                gload16(Ac + (size_t)ar * rowBytes + k0 * 2 + off, SMEM + c * 1024);
            } else {               // B chunks: rows 0..63
                int cc = c - 16;
                int row = cc * 8 + r8;
                int off = c16 ^ ((row & 7) << 4);
                gload16(Bc + (size_t)(n0 + row) * rowBytes + k0 * 2 + off,
                        SMEM + 16384 + cc * 1024);
            }
        }
        __syncthreads();
        #pragma unroll
        for (int ks = 0; ks < 2; ++ks) {
            bhalf8 af[2], bf[4];
            #pragma unroll
            for (int mi = 0; mi < 2; ++mi)
                af[mi] = *(const bhalf8*)(SMEM + swz((w * 32 + mi * 16 + ll) * 128 + ks * 64 + lg * 16));
            #pragma unroll
            for (int ni = 0; ni < 4; ++ni)
                bf[ni] = *(const bhalf8*)(SMEM + 16384 + swz((ni * 16 + ll) * 128 + ks * 64 + lg * 16));
            __builtin_amdgcn_s_setprio(1);
            #pragma unroll
            for (int mi = 0; mi < 2; ++mi)
                #pragma unroll
                for (int ni = 0; ni < 4; ++ni)
                    acc[mi][ni] = __builtin_amdgcn_mfma_f32_16x16x32_bf16(af[mi], bf[ni], acc[mi][ni], 0, 0, 0);
            __builtin_amdgcn_s_setprio(0);
        }
    }
    int type = n0 >> 9;  // 0 q, 1 k, >=2 v
    const float2* ct2 = (const float2*)ct;

    if (type >= 2) {  // ---- V: direct transposed bf16 writes (head = (n0-1024)>>6) ----
        int hd = (n0 - 1024) >> 6;
        #pragma unroll
        for (int ni = 0; ni < 4; ++ni) {
            int d = ni * 16 + ll;
            #pragma unroll
            for (int mi = 0; mi < 2; ++mi) {
                int rowL = m0 + w * 32 + mi * 16 + 4 * lg;
                if (COND == 0) {
                    int b = rowL >> 10, t = rowL & 1023;
                    uint2 pk = {cvtpk(acc[mi][ni][0], acc[mi][ni][1]),
                                cvtpk(acc[mi][ni][2], acc[mi][ni][3])};
                    *(uint2*)&vT[((size_t)(b * 8 + hd) * 64 + d) * VSTRIDE + t] = pk;
                } else {
                    #pragma unroll
                    for (int r = 0; r < 4; ++r) {
                        int row = rowL + r;
                        if (row < M) {
                            int b = row / 77, s = row - b * 77;
                            vT[((size_t)(b * 8 + hd) * 64 + d) * VSTRIDE + 1024 + s] =
                                f2bf(acc[mi][ni][r]);
                        }
                    }
                }
            }
        }
        return;
    }
    // ---- Q/K: RoPE + RMSNorm + scale, then LDS-transpose for coalesced stores ----
    const float* wnt = (type == 0) ? qn : kn;
    float wscale = (type == 0) ? 0.18033688011112042f : 1.0f;  // 0.125*log2e folded
    float sgn = (ll & 1) ? 1.f : -1.f;
    #pragma unroll
    for (int mi = 0; mi < 2; ++mi) {
        int rowL = m0 + w * 32 + mi * 16 + 4 * lg;
        int tt[4];
        #pragma unroll
        for (int r = 0; r < 4; ++r) {
            if (COND == 0) tt[r] = (rowL + r) & 1023;
            else {
                int row = rowL + r;
                if (row > M - 1) row = M - 1;
                int b = row / 77;
                tt[r] = 1024 + (row - b * 77);
            }
        }
        #pragma unroll
        for (int ni = 0; ni < 4; ++ni) {
            int jjv = (ni * 16 + ll) >> 1;
            f32x4 a = acc[mi][ni], p;
            #pragma unroll
            for (int r = 0; r < 4; ++r) p[r] = __shfl_xor(a[r], 1);
            #pragma unroll
            for (int r = 0; r < 4; ++r) {
                float2 cs = ct2[tt[r] * 32 + jjv];
                a[r] = fmaf(sgn * p[r], cs.y, a[r] * cs.x);
            }
            acc[mi][ni] = a;
        }
        f32x4 ss = {};
        #pragma unroll
        for (int ni = 0; ni < 4; ++ni)
            #pragma unroll
            for (int r = 0; r < 4; ++r) ss[r] = fmaf(acc[mi][ni][r], acc[mi][ni][r], ss[r]);
        #pragma unroll
        for (int msk = 1; msk < 16; msk <<= 1)
            #pragma unroll
            for (int r = 0; r < 4; ++r) ss[r] += __shfl_xor(ss[r], msk);
        #pragma unroll
        for (int r = 0; r < 4; ++r)
            ss[r] = rsqrtf(ss[r] * (1.0f / 64.f) + 1.1920929e-07f) * wscale;
        #pragma unroll
        for (int ni = 0; ni < 4; ++ni) {
            float wv = wnt[ni * 16 + ll];
            #pragma unroll
            for (int r = 0; r < 4; ++r) acc[mi][ni][r] *= ss[r] * wv;
        }
    }
    __syncthreads();
    unsigned short* stg = (unsigned short*)SMEM;  // [128][72]
    #pragma unroll
    for (int mi = 0; mi < 2; ++mi)
        #pragma unroll
        for (int ni = 0; ni < 4; ++ni) {
            int colL = ni * 16 + ll;
            int rowL = w * 32 + mi * 16 + 4 * lg;
            #pragma unroll
            for (int r = 0; r < 4; ++r)
                stg[(rowL + r) * 72 + colL] = f2bf(acc[mi][ni][r]);
        }
    __syncthreads();
    int rowO = tid >> 1, half = tid & 1;
    int rowG = m0 + rowO;
    if (COND == 1 && rowG >= M) return;
    int b, t;
    if (COND == 0) { b = rowG >> 10; t = rowG & 1023; }
    else { b = rowG / 77; t = 1024 + (rowG - b * 77); }
    unsigned short* dst;
    if (type == 0) dst = qb + ((size_t)(b * 8 + (n0 >> 6)) * HWN + t) * 64 + half * 32;
    else dst = kb + ((size_t)(b * 8 + ((n0 - 512) >> 6)) * TTOT + t) * 64 + half * 32;
    #pragma unroll
    for (int i = 0; i < 4; ++i)
        *(bhalf8*)&dst[i * 8] = *(const bhalf8*)&stg[rowO * 72 + half * 32 + i * 8];
}

// -------- attn v8: no-shift exp2 softmax, MFMA-accumulated L, double-buffered K/V --------
// LDS 40KB: buf0 K[0,8K) V[8K,16K); buf1 K[16K,24K) V[24K,32K); P [32K,40K).
__global__ __launch_bounds__(256) void k_attn_v8(const unsigned short* __restrict__ qb,
        const unsigned short* __restrict__ kbuf, const unsigned short* __restrict__ vT,
        unsigned short* __restrict__ ob) {
    __shared__ __align__(1024) char smc[40960];
    int f = blockIdx.x;
    int xcd = f & 7, n = f >> 3;
    int q0 = (n & 15) * 64;
    int bh = ((n >> 4) << 3) | xcd;
    int tid = threadIdx.x;
    int w = tid >> 6, l = tid & 63, lg = l >> 4, ll = l & 15;
    int r8 = l >> 3, c16 = (l & 7) * 16;
    bhalf8 qf[2];
    {
        const unsigned short* qbase = qb + ((size_t)bh * HWN + q0 + w * 16) * 64;
        #pragma unroll
        for (int ks = 0; ks < 2; ++ks)
            qf[ks] = *(const bhalf8*)&qbase[ll * 64 + ks * 32 + lg * 8];
    }
    bhalf8 onesf;
    #pragma unroll
    for (int i = 0; i < 8; ++i) onesf[i] = (short)0x3F80;  // bf16 1.0
    f32x4 accO[4] = {};   // O^T[d=d4*16+4lg+r][q=ll]
    f32x4 Lacc = {};      // all 4 rows = sum_k P[k][q=ll]
    const char* kgl = (const char*)kbuf + (size_t)bh * TTOT * 128;
    const char* vgl = (const char*)vT + (size_t)bh * 64 * (VSTRIDE * 2);
    char* pw = smc + 32768 + w * 2048 + ll * 128;
    int pswz = (ll & 7) << 4;

    auto stage = [&](int kt, int bsel) {
        char* base = smc + bsel * 16384;
        #pragma unroll
        for (int i = 0; i < 4; ++i) {
            int c = w * 4 + i;
            if (c < 8) {  // K chunk: rows = keys
                int row = c * 8 + r8;
                int t = kt * 64 + row;
                if (t > TTOT - 1) t = TTOT - 1;  // clamped rows are softmax-masked
                gload16(kgl + (size_t)t * 128 + (c16 ^ ((row & 7) << 4)), base + c * 1024);
            } else {      // V^T chunk: rows = d
                int row = (c - 8) * 8 + r8;
                gload16(vgl + (size_t)row * (VSTRIDE * 2) + kt * 128 + (c16 ^ ((row & 7) << 4)),
                        base + 8192 + (c - 8) * 1024);
            }
        }
    };
    stage(0, 0);
    __syncthreads();  // tile 0 landed
    for (int kt = 0; kt < 18; ++kt) {
        int cur = kt & 1;
        if (kt < 17) stage(kt + 1, cur ^ 1);  // issue next tile; latency hides under compute
        char* kl = smc + cur * 16384;
        char* vl = kl + 8192;
        // S^T = K x Q
        f32x4 s[4] = {};
        __builtin_amdgcn_s_setprio(1);
        #pragma unroll
        for (int ks = 0; ks < 2; ++ks) {
            bhalf8 kf[4];
            #pragma unroll
            for (int k4 = 0; k4 < 4; ++k4)
                kf[k4] = *(const bhalf8*)(kl + swz((k4 * 16 + ll) * 128 + ks * 64 + lg * 16));
            #pragma unroll
            for (int k4 = 0; k4 < 4; ++k4)
                s[k4] = __builtin_amdgcn_mfma_f32_16x16x32_bf16(kf[k4], qf[ks], s[k4], 0, 0, 0);
        }
        __builtin_amdgcn_s_setprio(0);
        if (kt == 17) {  // mask tail keys (key index lane-local: k4*16 + 4lg + r)
            int kb0 = kt * 64 + 4 * lg;
            #pragma unroll
            for (int k4 = 0; k4 < 4; ++k4)
                #pragma unroll
                for (int r = 0; r < 4; ++r)
                    if (kb0 + k4 * 16 + r >= TTOT) s[k4][r] = -1e30f;
        }
        // softmax, no shift: P = exp2(s); uniform scale cancels in O=PV/L.
        #pragma unroll
        for (int k4 = 0; k4 < 4; ++k4) {
            float p0 = exp2f(s[k4][0]), p1 = exp2f(s[k4][1]);
            float p2 = exp2f(s[k4][2]), p3 = exp2f(s[k4][3]);
            uint2 pk = {cvtpk(p0, p1), cvtpk(p2, p3)};
            *(uint2*)(pw + ((k4 * 32 + lg * 8) ^ pswz)) = pk;
        }
        // O^T += V^T x P ; L += ones x P
        __builtin_amdgcn_s_setprio(1);
        #pragma unroll
        for (int ks = 0; ks < 2; ++ks) {
            bhalf8 vf[4];
            #pragma unroll
            for (int d4 = 0; d4 < 4; ++d4)
                vf[d4] = *(const bhalf8*)(vl + swz((d4 * 16 + ll) * 128 + ks * 64 + lg * 16));
            bhalf8 pf = *(const bhalf8*)(smc + 32768 + w * 2048 + swz(ll * 128 + ks * 64 + lg * 16));
            Lacc = __builtin_amdgcn_mfma_f32_16x16x32_bf16(onesf, pf, Lacc, 0, 0, 0);
            #pragma unroll
            for (int d4 = 0; d4 < 4; ++d4)
                accO[d4] = __builtin_amdgcn_mfma_f32_16x16x32_bf16(vf[d4], pf, accO[d4], 0, 0, 0);
        }
        __builtin_amdgcn_s_setprio(0);
        __syncthreads();  // next-tile loads landed; all waves done with cur buffers
    }
    // epilogue: /L, transpose O^T -> [q][d] via LDS, coalesced stores
    {
        float inv = 1.0f / Lacc[0];
        int orow = w * 16 + ll;
        char* po = smc + orow * 128;
        int oswz = (orow & 7) << 4;
        #pragma unroll
        for (int d4 = 0; d4 < 4; ++d4) {
            uint2 pk = {cvtpk(accO[d4][0] * inv, accO[d4][1] * inv),
                        cvtpk(accO[d4][2] * inv, accO[d4][3] * inv)};
            *(uint2*)(po + ((d4 * 32 + lg * 8) ^ oswz)) = pk;
        }
    }
    __syncthreads();
    int b = bh >> 3, h = bh & 7;
    int row = tid >> 2, seg = tid & 3;
    bhalf8 v0 = *(const bhalf8*)(smc + swz(row * 128 + seg * 32));
    bhalf8 v1 = *(const bhalf8*)(smc + swz(row * 128 + seg * 32 + 16));
    unsigned short* dst = ob + ((size_t)(b * HWN + q0 + row)) * CH + h * 64 + seg * 16;
    *(bhalf8*)&dst[0] = v0;
    *(bhalf8*)&dst[8] = v1;
}

extern "C" void kernel_launch(void* const* d_in, const int* in_sizes, int n_in,
                              void* d_out, int out_size, void* d_ws, size_t ws_size,
                              hipStream_t stream) {
    const float* x     = (const float*)d_in[0];
    const float* cond  = (const float*)d_in[1];
    const float* femb  = (const float*)d_in[2];
    const float* mod_w = (const float*)d_in[3];
    const float* mod_b = (const float*)d_in[4];
    const float* n1s   = (const float*)d_in[5];
    const float* n2s   = (const float*)d_in[6];
    const float* qkvsw = (const float*)d_in[7];
    const float* qkvcw = (const float*)d_in[8];
    const float* ropef = (const float*)d_in[9];
    const float* qn    = (const float*)d_in[10];
    const float* kn    = (const float*)d_in[11];
    const float* outw  = (const float*)d_in[12];
    const float* outb  = (const float*)d_in[13];
    const float* w1    = (const float*)d_in[14];
    const float* b1    = (const float*)d_in[15];
    const float* w2    = (const float*)d_in[16];
    const float* b2    = (const float*)d_in[17];
    float* out = (float*)d_out;
    char* W = (char*)d_ws;

    // byte layout (~95.5 MB peak)
    unsigned short* wqs_b = (unsigned short*)(W + 0);         // 1536x512
    unsigned short* wqc_b = (unsigned short*)(W + 1572864);   // 1536x768
    unsigned short* wo_b  = (unsigned short*)(W + 3932160);   // 512x512
    unsigned short* w1_b  = (unsigned short*)(W + 4456448);   // 2048x512
    unsigned short* w2_b  = (unsigned short*)(W + 6553600);   // 512x2048
    unsigned short* condb = (unsigned short*)(W + 8650752);   // 616x768
    float* mod            = (float*)(W + 9596928);            // 8x3072
    float* ct             = (float*)(W + 9695232);            // 1101x32 float2
    unsigned short* hmod  = (unsigned short*)(W + 9977088);   // 8192x512 bf16
    unsigned short* obuf  = hmod;                             // overlays hmod (dead post-qkv)
    unsigned short* qbuf  = (unsigned short*)(W + 18365696);  // 64x1024x64 bf16
    unsigned short* kbuf  = (unsigned short*)(W + 26754304);  // 64x1101x64 bf16
    unsigned short* vTb   = (unsigned short*)(W + 35772672);  // 64x64x1152 bf16
    unsigned short* h2    = vTb;                              // overlays vT (dead post-attn)
    unsigned short* mbuf  = (unsigned short*)(W + 45209856);  // 8192x2048 bf16
    float* x1             = (float*)(W + 78764288);           // 8x512x1024 f32
    float* sebuf          = (float*)(W + 45209920);           // 8x768 f32 (pre-MLP1 liveness)

    PrepArgs pa;
    pa.src[0] = qkvsw; pa.dst[0] = wqs_b; pa.n[0] = 1536 * 512;
    pa.src[1] = qkvcw; pa.dst[1] = wqc_b; pa.n[1] = 1536 * 768;
    pa.src[2] = outw;  pa.dst[2] = wo_b;  pa.n[2] = 512 * 512;
    pa.src[3] = w1;    pa.dst[3] = w1_b;  pa.n[3] = 2048 * 512;
    pa.src[4] = w2;    pa.dst[4] = w2_b;  pa.n[4] = 512 * 2048;
    pa.src[5] = cond;  pa.dst[5] = condb; pa.n[5] = 616 * 768;
    pa.freqs = ropef; pa.ct = ct;
    pa.emb = femb; pa.mbias = mod_b; pa.mod = mod; pa.se = sebuf;
    k_prep<<<dim3(1152, 8), 256, 0, stream>>>(pa);
    k_mod<<<dim3(12, 8, 8), 256, 0, stream>>>(sebuf, mod_w, mod);

    k_rms2d_mod_t<<<dim3(16, BATCH), 256, 0, stream>>>(x, n1s, mod, 0, 512, hmod);
    // qkv (spatial): fused RoPE/RMS/V^T epilogue, 128x64 tiles, grid (m,n)
    k_gemm_qkv<0><<<dim3(64, 24), 256, 0, stream>>>(hmod, wqs_b, ct, qn, kn,
                                                    qbuf, kbuf, vTb);
    // qkv (cond): k/v tiles only (nOff=512), grid (m,n)
    k_gemm_qkv<1><<<dim3(5, 16), 256, 0, stream>>>(condb, wqc_b, ct, qn, kn,
                                                   qbuf, kbuf, vTb);
    k_attn_v8<<<dim3(1024), 256, 0, stream>>>(qbuf, kbuf, vTb, obuf);
    // out-proj: x1 = x + g1*(obuf @ Wo^T + outb)  (channel-major f32), grid (m,n)
    k_gemm_mfma<1, 128, 64><<<dim3(64, 8), 256, 0, stream>>>(
        obuf, wo_b, x1, 8192, 512, 512, outb, mod + 2 * 512, x);
    k_rms2d_mod_t<<<dim3(16, BATCH), 256, 0, stream>>>(x1, n2s, mod, 3 * 512, 4 * 512, h2);
    // MLP1 + fast gelu -> bf16 [8192,2048], 128x128, grid (m,n)
    k_gemm_mfma<2, 128, 128><<<dim3(64, 16), 256, 0, stream>>>(
        h2, w1_b, mbuf, 8192, 2048, 512, b1, nullptr, nullptr);
    // MLP2 + gate + residual -> d_out (channel-major f32), grid (m,n)
    k_gemm_mfma<1, 128, 64><<<dim3(64, 8), 256, 0, stream>>>(
        mbuf, w2_b, out, 8192, 512, 2048, b2, mod + 5 * 512, x1);
}